// Round 1
// baseline (1863.500 us; speedup 1.0000x reference)
//
#include <hip/hip_runtime.h>
#include <hip/hip_bf16.h>
#include <math.h>

// GoldenMoE: B=2,T=2048,D=2048,E=8,F=2048.  out = sum_e w[bt,e] * ((silu(X Wg_e) * (X Wu_e)) Wd_e)
// Strategy: bf16 MFMA GEMMs (m97 128x128 structure), per-expert transposed bf16 weights in ws.

#define D_DIM 2048
#define F_DIM 2048
#define E_NUM 8
#define BT_NUM 4096

typedef short short8 __attribute__((ext_vector_type(8)));
typedef float f32x4 __attribute__((ext_vector_type(4)));

__device__ __forceinline__ short f2bf(float f) {
  __hip_bfloat16 h = __float2bfloat16(f);
  return __builtin_bit_cast(short, h);
}
__device__ __forceinline__ float bf2f(short s) {
  __hip_bfloat16 h = __builtin_bit_cast(__hip_bfloat16, s);
  return __bfloat162float(h);
}

// ---------------- router: weights [BT][8] f32 ----------------
__global__ __launch_bounds__(256) void router_kernel(
    const float* __restrict__ x, const float* __restrict__ Wr,
    const float* __restrict__ temp, float* __restrict__ rw)
{
  const int bt = blockIdx.x;
  const int tid = threadIdx.x;
  const float* xp = x + (size_t)bt * D_DIM;
  float acc[E_NUM];
#pragma unroll
  for (int e = 0; e < E_NUM; e++) acc[e] = 0.f;
  for (int d = tid; d < D_DIM; d += 256) {
    float xv = xp[d];
    const float* wr = Wr + (size_t)d * E_NUM;
#pragma unroll
    for (int e = 0; e < E_NUM; e++) acc[e] += xv * wr[e];
  }
#pragma unroll
  for (int e = 0; e < E_NUM; e++) {
    float v = acc[e];
#pragma unroll
    for (int off = 32; off > 0; off >>= 1) v += __shfl_down(v, off, 64);
    acc[e] = v;
  }
  __shared__ float part[4][E_NUM];
  const int wid = tid >> 6, lane = tid & 63;
  if (lane == 0) {
#pragma unroll
    for (int e = 0; e < E_NUM; e++) part[wid][e] = acc[e];
  }
  __syncthreads();
  if (tid == 0) {
    const float t = temp[0];
    float wz[E_NUM], fb[E_NUM];
    float wsum = 0.f;
#pragma unroll
    for (int e = 0; e < E_NUM; e++) {
      float l = part[0][e] + part[1][e] + part[2][e] + part[3][e];
      float ih = 1.f / (1.f + expf(-l / t));
      float ds = fabsf(ih - 0.36787944117144233f);  // 1/e
      float in_zone = (ih >= 0.21231792754821915f && ih <= 0.5f) ? 1.f : 0.f;
      wz[e] = expf(-ds / 0.1f) * in_zone;
      wsum += wz[e];
      fb[e] = expf(-ds / 0.3f);
    }
    float w[E_NUM];
    if (wsum < 1e-8f) {
      int i1 = 0;
#pragma unroll
      for (int e = 1; e < E_NUM; e++) if (fb[e] > fb[i1]) i1 = e;
      int i2 = -1;
#pragma unroll
      for (int e = 0; e < E_NUM; e++) if (e != i1 && (i2 < 0 || fb[e] > fb[i2])) i2 = e;
      float s = fmaxf(fb[i1] + fb[i2], 1e-8f);
#pragma unroll
      for (int e = 0; e < E_NUM; e++) w[e] = (e == i1 || e == i2) ? fb[e] / s : 0.f;
    } else {
#pragma unroll
      for (int e = 0; e < E_NUM; e++) w[e] = wz[e];
    }
    float s2 = 0.f;
#pragma unroll
    for (int e = 0; e < E_NUM; e++) s2 += w[e];
    s2 = fmaxf(s2, 1e-8f);
    float inv = 1.f / s2;
#pragma unroll
    for (int e = 0; e < E_NUM; e++) rw[(size_t)bt * E_NUM + e] = w[e] * inv;
  }
}

// ------------- transpose + f32->bf16 (3 matrices, 2048x2048) -------------
__global__ __launch_bounds__(256) void transpose_cvt_kernel(
    const float* __restrict__ s0, const float* __restrict__ s1, const float* __restrict__ s2,
    short* __restrict__ d0, short* __restrict__ d1, short* __restrict__ d2)
{
  const float* s; short* d;
  if (blockIdx.z == 0) { s = s0; d = d0; }
  else if (blockIdx.z == 1) { s = s1; d = d1; }
  else { s = s2; d = d2; }
  __shared__ float t[32][33];
  const int tx = threadIdx.x, ty = threadIdx.y;
  const int x0 = blockIdx.x * 32, y0 = blockIdx.y * 32;
#pragma unroll
  for (int i = ty; i < 32; i += 8) t[i][tx] = s[(size_t)(y0 + i) * D_DIM + x0 + tx];
  __syncthreads();
#pragma unroll
  for (int i = ty; i < 32; i += 8) d[(size_t)(x0 + i) * D_DIM + y0 + tx] = f2bf(t[tx][i]);
}

// ------------- GEMM 128x128 tile, BK=32, 4 waves, mfma 16x16x32 bf16 -------------
// A [M][K] (f32 if AF32 else bf16), Bt = B^T [N][K] bf16.
// EPI 0: gbuf = bf16(acc)            (gate)
// EPI 1: gbuf = bf16(silu(gbuf)*acc) (h, in-place)
// EPI 2: out (+)= rw[row][e]*acc     (e==0 writes)
template<int AF32, int EPI>
__global__ __launch_bounds__(256) void gemm_kernel(
    const void* __restrict__ Ap, const short* __restrict__ Bt,
    short* __restrict__ gbuf, float* __restrict__ outp,
    const float* __restrict__ rw, int expert, int M, int N, int K)
{
  __shared__ short As[128][40];   // +8 pad: 80B rows, 16B-aligned
  __shared__ short Bs[128][32];   // linear (global_load_lds dest)
  const int tid = threadIdx.x;
  const int m0 = blockIdx.y * 128, n0 = blockIdx.x * 128;
  const int w = tid >> 6, lane = tid & 63;
  const int wm = w >> 1, wn = w & 1;
  const int r = lane & 15, g = lane >> 4;

  f32x4 acc[4][4];
#pragma unroll
  for (int m = 0; m < 4; m++)
#pragma unroll
    for (int n = 0; n < 4; n++) acc[m][n] = (f32x4){0.f, 0.f, 0.f, 0.f};

  const int arow = tid >> 1, acol = (tid & 1) * 16;

  for (int k0 = 0; k0 < K; k0 += 32) {
    // B tile: 128 rows x 32 k, 8 x global_load_lds_dwordx4 (2 per wave)
#pragma unroll
    for (int i = 0; i < 2; i++) {
      const int Rb = 32 * w + 16 * i;
      const short* gp = Bt + (size_t)(n0 + Rb + (lane >> 2)) * K + k0 + (lane & 3) * 8;
      __builtin_amdgcn_global_load_lds(
          (const __attribute__((address_space(1))) unsigned int*)gp,
          (__attribute__((address_space(3))) unsigned int*)&Bs[Rb][0],
          16, 0, 0);
    }
    // A tile: reg-staged (f32->bf16 convert, or direct bf16)
    if (AF32) {
      const float* ap = (const float*)Ap + (size_t)(m0 + arow) * K + k0 + acol;
      f32x4 v0 = ((const f32x4*)ap)[0];
      f32x4 v1 = ((const f32x4*)ap)[1];
      f32x4 v2 = ((const f32x4*)ap)[2];
      f32x4 v3 = ((const f32x4*)ap)[3];
      short8 p0, p1;
#pragma unroll
      for (int j = 0; j < 4; j++) {
        p0[j] = f2bf(v0[j]); p0[4 + j] = f2bf(v1[j]);
        p1[j] = f2bf(v2[j]); p1[4 + j] = f2bf(v3[j]);
      }
      *(short8*)&As[arow][acol] = p0;
      *(short8*)&As[arow][acol + 8] = p1;
    } else {
      const short* ap = (const short*)Ap + (size_t)(m0 + arow) * K + k0 + acol;
      short8 p0 = ((const short8*)ap)[0];
      short8 p1 = ((const short8*)ap)[1];
      *(short8*)&As[arow][acol] = p0;
      *(short8*)&As[arow][acol + 8] = p1;
    }
    __syncthreads();

    short8 af[4], bfr[4];
#pragma unroll
    for (int m = 0; m < 4; m++) af[m] = *(const short8*)&As[wm * 64 + m * 16 + r][g * 8];
#pragma unroll
    for (int n = 0; n < 4; n++) bfr[n] = *(const short8*)&Bs[wn * 64 + n * 16 + r][g * 8];
#pragma unroll
    for (int m = 0; m < 4; m++)
#pragma unroll
      for (int n = 0; n < 4; n++)
        asm volatile("v_mfma_f32_16x16x32_bf16 %0, %1, %2, %0"
                     : "+v"(acc[m][n]) : "v"(af[m]), "v"(bfr[n]));
    __syncthreads();
  }
  __builtin_amdgcn_sched_barrier(0);
  asm volatile("s_nop 7\n\ts_nop 7" ::: "memory");

  const int rowbase = m0 + wm * 64;
  const int colbase = n0 + wn * 64;
#pragma unroll
  for (int m = 0; m < 4; m++) {
#pragma unroll
    for (int n = 0; n < 4; n++) {
      const int col = colbase + n * 16 + r;
#pragma unroll
      for (int j = 0; j < 4; j++) {
        const int row = rowbase + m * 16 + g * 4 + j;
        const float v = acc[m][n][j];
        const size_t idx = (size_t)row * N + col;
        if (EPI == 0) {
          gbuf[idx] = f2bf(v);
        } else if (EPI == 1) {
          float gv = bf2f(gbuf[idx]);
          float hv = (gv / (1.f + __expf(-gv))) * v;   // silu(g)*u
          gbuf[idx] = f2bf(hv);
        } else {
          float wt = rw[(size_t)row * 8 + expert];
          if (expert == 0) outp[idx] = wt * v;
          else             outp[idx] += wt * v;
        }
      }
    }
  }
}

extern "C" void kernel_launch(void* const* d_in, const int* in_sizes, int n_in,
                              void* d_out, int out_size, void* d_ws, size_t ws_size,
                              hipStream_t stream)
{
  const float* x  = (const float*)d_in[0];
  const float* Wg = (const float*)d_in[1];
  const float* Wu = (const float*)d_in[2];
  const float* Wd = (const float*)d_in[3];
  const float* Wr = (const float*)d_in[4];
  const float* tp = (const float*)d_in[5];
  float* out = (float*)d_out;

  char* ws = (char*)d_ws;
  float* rw = (float*)ws;                       // 4096*8*4 = 128 KiB
  size_t off = 131072;
  short* WTg = (short*)(ws + off); off += (size_t)2048 * 2048 * 2;  // 8 MiB each
  short* WTu = (short*)(ws + off); off += (size_t)2048 * 2048 * 2;
  short* WTd = (short*)(ws + off); off += (size_t)2048 * 2048 * 2;
  short* gbuf = (short*)(ws + off);             // [4096][2048] bf16 gate->h

  router_kernel<<<4096, 256, 0, stream>>>(x, Wr, tp, rw);

  for (int e = 0; e < 8; e++) {
    const float* wg = Wg + (size_t)e * 2048 * 2048;
    const float* wu = Wu + (size_t)e * 2048 * 2048;
    const float* wd = Wd + (size_t)e * 2048 * 2048;
    transpose_cvt_kernel<<<dim3(64, 64, 3), dim3(32, 8), 0, stream>>>(
        wg, wu, wd, WTg, WTu, WTd);
    // gate = X @ Wg_e
    gemm_kernel<1, 0><<<dim3(16, 32), 256, 0, stream>>>(
        (const void*)x, WTg, gbuf, nullptr, nullptr, e, BT_NUM, F_DIM, D_DIM);
    // h = silu(gate) * (X @ Wu_e)   (in-place in gbuf)
    gemm_kernel<1, 1><<<dim3(16, 32), 256, 0, stream>>>(
        (const void*)x, WTu, gbuf, nullptr, nullptr, e, BT_NUM, F_DIM, D_DIM);
    // out (+)= w[:,e] * (h @ Wd_e)
    gemm_kernel<0, 2><<<dim3(16, 32), 256, 0, stream>>>(
        (const void*)gbuf, WTd, nullptr, out, rw, e, BT_NUM, D_DIM, F_DIM);
  }
}

// Round 2
// 1310.781 us; speedup vs baseline: 1.4217x; 1.4217x over previous
//
#include <hip/hip_runtime.h>
#include <hip/hip_bf16.h>
#include <math.h>

// GoldenMoE: B=2,T=2048,D=2048,E=8,F=2048.
// out = sum_e w[bt,e] * ((silu(X Wg_e) * (X Wu_e)) Wd_e)
// Round 2: bf16 A via global_load_lds, T2 XOR-swizzled LDS (both-sides),
// fused gate+up (w folded into h'), single K=16384 down GEMM, expert-batched grid.

#define D_DIM 2048
#define E_NUM 8
#define BT_NUM 4096
#define MAT_ELEMS (2048u * 2048u)

typedef short short8 __attribute__((ext_vector_type(8)));
typedef float f32x4 __attribute__((ext_vector_type(4)));

__device__ __forceinline__ short f2bf(float f) {
  __hip_bfloat16 h = __float2bfloat16(f);
  return __builtin_bit_cast(short, h);
}

#define GLOAD_LDS(gptr, lptr) \
  __builtin_amdgcn_global_load_lds( \
      (const __attribute__((address_space(1))) unsigned int*)(gptr), \
      (__attribute__((address_space(3))) unsigned int*)(lptr), 16, 0, 0)

// ---------------- router: weights [BT][8] f32 ----------------
__global__ __launch_bounds__(256) void router_kernel(
    const float* __restrict__ x, const float* __restrict__ Wr,
    const float* __restrict__ temp, float* __restrict__ rw)
{
  const int bt = blockIdx.x;
  const int tid = threadIdx.x;
  const float* xp = x + (size_t)bt * D_DIM;
  float acc[E_NUM];
#pragma unroll
  for (int e = 0; e < E_NUM; e++) acc[e] = 0.f;
  for (int d = tid; d < D_DIM; d += 256) {
    float xv = xp[d];
    const float* wr = Wr + (size_t)d * E_NUM;
#pragma unroll
    for (int e = 0; e < E_NUM; e++) acc[e] += xv * wr[e];
  }
#pragma unroll
  for (int e = 0; e < E_NUM; e++) {
    float v = acc[e];
#pragma unroll
    for (int off = 32; off > 0; off >>= 1) v += __shfl_down(v, off, 64);
    acc[e] = v;
  }
  __shared__ float part[4][E_NUM];
  const int wid = tid >> 6, lane = tid & 63;
  if (lane == 0) {
#pragma unroll
    for (int e = 0; e < E_NUM; e++) part[wid][e] = acc[e];
  }
  __syncthreads();
  if (tid == 0) {
    const float t = temp[0];
    float wz[E_NUM], fb[E_NUM];
    float wsum = 0.f;
#pragma unroll
    for (int e = 0; e < E_NUM; e++) {
      float l = part[0][e] + part[1][e] + part[2][e] + part[3][e];
      float ih = 1.f / (1.f + expf(-l / t));
      float ds = fabsf(ih - 0.36787944117144233f);  // 1/e
      float in_zone = (ih >= 0.21231792754821915f && ih <= 0.5f) ? 1.f : 0.f;
      wz[e] = expf(-ds / 0.1f) * in_zone;
      wsum += wz[e];
      fb[e] = expf(-ds / 0.3f);
    }
    float w[E_NUM];
    if (wsum < 1e-8f) {
      int i1 = 0;
#pragma unroll
      for (int e = 1; e < E_NUM; e++) if (fb[e] > fb[i1]) i1 = e;
      int i2 = -1;
#pragma unroll
      for (int e = 0; e < E_NUM; e++) if (e != i1 && (i2 < 0 || fb[e] > fb[i2])) i2 = e;
      float s = fmaxf(fb[i1] + fb[i2], 1e-8f);
#pragma unroll
      for (int e = 0; e < E_NUM; e++) w[e] = (e == i1 || e == i2) ? fb[e] / s : 0.f;
    } else {
#pragma unroll
      for (int e = 0; e < E_NUM; e++) w[e] = wz[e];
    }
    float s2 = 0.f;
#pragma unroll
    for (int e = 0; e < E_NUM; e++) s2 += w[e];
    s2 = fmaxf(s2, 1e-8f);
    float inv = 1.f / s2;
#pragma unroll
    for (int e = 0; e < E_NUM; e++) rw[(size_t)bt * E_NUM + e] = w[e] * inv;
  }
}

// ---------------- x f32 -> bf16 ----------------
__global__ __launch_bounds__(256) void cvt_x_kernel(
    const float* __restrict__ x, short* __restrict__ xb)
{
  const size_t gid = (size_t)blockIdx.x * 256 + threadIdx.x;
  const size_t base = gid * 8;
  f32x4 v0 = *(const f32x4*)(x + base);
  f32x4 v1 = *(const f32x4*)(x + base + 4);
  short8 p;
#pragma unroll
  for (int j = 0; j < 4; j++) { p[j] = f2bf(v0[j]); p[4 + j] = f2bf(v1[j]); }
  *(short8*)(xb + base) = p;
}

// ------------- transpose + f32->bf16 -------------
// z in [0, 3*nexp): which = z/nexp (0:Wg,1:Wu,2:Wd), e = z%nexp.
// Wg/Wu -> per-expert [N][K] blocks; Wd -> WdT[n][e*2048+k] (stride nexp*2048).
__global__ __launch_bounds__(256) void transpose_cvt_kernel(
    const float* __restrict__ sg, const float* __restrict__ su, const float* __restrict__ sd,
    short* __restrict__ dg, short* __restrict__ du, short* __restrict__ dd, int nexp)
{
  const int which = blockIdx.z / nexp, e = blockIdx.z % nexp;
  const float* s; short* d; size_t dstride, dcol0;
  if (which == 0)      { s = sg + (size_t)e * MAT_ELEMS; d = dg + (size_t)e * MAT_ELEMS; dstride = 2048; dcol0 = 0; }
  else if (which == 1) { s = su + (size_t)e * MAT_ELEMS; d = du + (size_t)e * MAT_ELEMS; dstride = 2048; dcol0 = 0; }
  else                 { s = sd + (size_t)e * MAT_ELEMS; d = dd; dstride = (size_t)nexp * 2048; dcol0 = (size_t)e * 2048; }
  __shared__ float t[32][33];
  const int tx = threadIdx.x, ty = threadIdx.y;
  const int x0 = blockIdx.x * 32, y0 = blockIdx.y * 32;
#pragma unroll
  for (int i = ty; i < 32; i += 8) t[i][tx] = s[(size_t)(y0 + i) * 2048 + x0 + tx];
  __syncthreads();
#pragma unroll
  for (int i = ty; i < 32; i += 8)
    d[(size_t)(x0 + i) * dstride + dcol0 + y0 + tx] = f2bf(t[tx][i]);
}

// ================= GEMM cores =================
// Shared geometry: 128x128 tile, BK=32, 4 waves (2x2), 16x16x32 bf16 MFMA.
// LDS rows: 32 shorts = 64B = 4 chunks of 16B. Physical chunk = logical ^ (row&3)
// (T2 swizzle; applied on the global SOURCE for global_load_lds, and on reads).

// fused gate+up: A = xb[4096][2048] bf16; Bg/Bu = WT (per-expert [2048][2048]).
// h'[row][ez*h_e_mult + col] = bf16( silu(g)*u * rw[row*8+e] ), row stride h_stride.
__global__ __launch_bounds__(256, 2) void fused_gu_kernel(
    const short* __restrict__ xb, const short* __restrict__ WTg,
    const short* __restrict__ WTu, short* __restrict__ h,
    const float* __restrict__ rw, int e_base, long h_stride, int h_e_mult)
{
  __shared__ short As[128 * 32];
  __shared__ short Bg[128 * 32];
  __shared__ short Bu[128 * 32];
  const int tid = threadIdx.x;
  const int ez = blockIdx.z, e = e_base + ez;
  const int m0 = blockIdx.y * 128, n0 = blockIdx.x * 128;
  const int w = tid >> 6, lane = tid & 63;
  const int wm = w >> 1, wn = w & 1;
  const int r = lane & 15, g4 = lane >> 4;
  const short* Bgp = WTg + (size_t)ez * MAT_ELEMS;
  const short* Bup = WTu + (size_t)ez * MAT_ELEMS;

  f32x4 ag[4][4], au[4][4];
#pragma unroll
  for (int m = 0; m < 4; m++)
#pragma unroll
    for (int n = 0; n < 4; n++) { ag[m][n] = (f32x4){0,0,0,0}; au[m][n] = (f32x4){0,0,0,0}; }

  const int srow = lane >> 2;                    // row within 16-row group
  const int schunk = (lane & 3) ^ (srow & 3);    // pre-swizzled source chunk
  const int K = 2048;

  for (int k0 = 0; k0 < K; k0 += 32) {
#pragma unroll
    for (int i = 0; i < 2; i++) {
      const int Rb = w * 32 + i * 16;
      const int row = Rb + srow;
      const size_t co = (size_t)(k0 + schunk * 8);
      GLOAD_LDS(xb  + (size_t)(m0 + row) * K + co, As + Rb * 32);
      GLOAD_LDS(Bgp + (size_t)(n0 + row) * K + co, Bg + Rb * 32);
      GLOAD_LDS(Bup + (size_t)(n0 + row) * K + co, Bu + Rb * 32);
    }
    __syncthreads();

    short8 af[4], bg[4], bu[4];
#pragma unroll
    for (int m = 0; m < 4; m++) {
      const int row = wm * 64 + m * 16 + r;
      af[m] = *(const short8*)(As + row * 32 + ((g4 ^ (r & 3)) * 8));
    }
#pragma unroll
    for (int n = 0; n < 4; n++) {
      const int row = wn * 64 + n * 16 + r;
      const int c = (g4 ^ (r & 3)) * 8;
      bg[n] = *(const short8*)(Bg + row * 32 + c);
      bu[n] = *(const short8*)(Bu + row * 32 + c);
    }
#pragma unroll
    for (int m = 0; m < 4; m++)
#pragma unroll
      for (int n = 0; n < 4; n++) {
        asm volatile("v_mfma_f32_16x16x32_bf16 %0, %1, %2, %0"
                     : "+v"(ag[m][n]) : "v"(af[m]), "v"(bg[n]));
        asm volatile("v_mfma_f32_16x16x32_bf16 %0, %1, %2, %0"
                     : "+v"(au[m][n]) : "v"(af[m]), "v"(bu[n]));
      }
    __syncthreads();
  }
  __builtin_amdgcn_sched_barrier(0);
  asm volatile("s_nop 7\n\ts_nop 7" ::: "memory");

  const int rowbase = m0 + wm * 64;
  const int colbase = n0 + wn * 64;
  const long hcol0 = (long)ez * h_e_mult;
#pragma unroll
  for (int m = 0; m < 4; m++) {
#pragma unroll
    for (int n = 0; n < 4; n++) {
      const int col = colbase + n * 16 + r;
#pragma unroll
      for (int j = 0; j < 4; j++) {
        const int row = rowbase + m * 16 + g4 * 4 + j;
        const float gv = ag[m][n][j];
        const float uv = au[m][n][j];
        const float wt = rw[(size_t)row * 8 + e];
        const float hv = (gv / (1.f + __expf(-gv))) * uv * wt;
        h[(size_t)row * h_stride + hcol0 + col] = f2bf(hv);
      }
    }
  }
}

// down: out[4096][2048] f32 = A[4096][K] @ BtT, Bt = [2048][K] bf16.
__global__ __launch_bounds__(256, 2) void down_kernel(
    const short* __restrict__ A, const short* __restrict__ Bt,
    float* __restrict__ out, int K, int accum)
{
  __shared__ short As[128 * 32];
  __shared__ short Bs[128 * 32];
  const int tid = threadIdx.x;
  const int m0 = blockIdx.y * 128, n0 = blockIdx.x * 128;
  const int w = tid >> 6, lane = tid & 63;
  const int wm = w >> 1, wn = w & 1;
  const int r = lane & 15, g4 = lane >> 4;

  f32x4 acc[4][4];
#pragma unroll
  for (int m = 0; m < 4; m++)
#pragma unroll
    for (int n = 0; n < 4; n++) acc[m][n] = (f32x4){0,0,0,0};

  const int srow = lane >> 2;
  const int schunk = (lane & 3) ^ (srow & 3);

  for (int k0 = 0; k0 < K; k0 += 32) {
#pragma unroll
    for (int i = 0; i < 2; i++) {
      const int Rb = w * 32 + i * 16;
      const int row = Rb + srow;
      const size_t co = (size_t)(k0 + schunk * 8);
      GLOAD_LDS(A  + (size_t)(m0 + row) * K + co, As + Rb * 32);
      GLOAD_LDS(Bt + (size_t)(n0 + row) * K + co, Bs + Rb * 32);
    }
    __syncthreads();

    short8 af[4], bfr[4];
#pragma unroll
    for (int m = 0; m < 4; m++) {
      const int row = wm * 64 + m * 16 + r;
      af[m] = *(const short8*)(As + row * 32 + ((g4 ^ (r & 3)) * 8));
    }
#pragma unroll
    for (int n = 0; n < 4; n++) {
      const int row = wn * 64 + n * 16 + r;
      bfr[n] = *(const short8*)(Bs + row * 32 + ((g4 ^ (r & 3)) * 8));
    }
#pragma unroll
    for (int m = 0; m < 4; m++)
#pragma unroll
      for (int n = 0; n < 4; n++)
        asm volatile("v_mfma_f32_16x16x32_bf16 %0, %1, %2, %0"
                     : "+v"(acc[m][n]) : "v"(af[m]), "v"(bfr[n]));
    __syncthreads();
  }
  __builtin_amdgcn_sched_barrier(0);
  asm volatile("s_nop 7\n\ts_nop 7" ::: "memory");

  const int rowbase = m0 + wm * 64;
  const int colbase = n0 + wn * 64;
#pragma unroll
  for (int m = 0; m < 4; m++) {
#pragma unroll
    for (int n = 0; n < 4; n++) {
      const int col = colbase + n * 16 + r;
#pragma unroll
      for (int j = 0; j < 4; j++) {
        const int row = rowbase + m * 16 + g4 * 4 + j;
        const size_t idx = (size_t)row * 2048 + col;
        const float v = acc[m][n][j];
        if (accum) out[idx] += v; else out[idx] = v;
      }
    }
  }
}

extern "C" void kernel_launch(void* const* d_in, const int* in_sizes, int n_in,
                              void* d_out, int out_size, void* d_ws, size_t ws_size,
                              hipStream_t stream)
{
  const float* x  = (const float*)d_in[0];
  const float* Wg = (const float*)d_in[1];
  const float* Wu = (const float*)d_in[2];
  const float* Wd = (const float*)d_in[3];
  const float* Wr = (const float*)d_in[4];
  const float* tp = (const float*)d_in[5];
  float* out = (float*)d_out;

  char* ws = (char*)d_ws;
  const size_t SZ_RW  = (size_t)BT_NUM * 8 * 4;            // 128 KiB
  const size_t SZ_XB  = (size_t)BT_NUM * 2048 * 2;         // 16 MiB
  const size_t SZ_MAT = (size_t)MAT_ELEMS * 2;             // 8 MiB

  // batched layout: rw, xb, WTg[8], WTu[8], WdT[2048][16384], h[4096][16384]
  const size_t FULL = SZ_RW + SZ_XB + 8 * SZ_MAT * 2 + 8 * SZ_MAT + (size_t)BT_NUM * 16384 * 2;

  router_kernel<<<BT_NUM, 256, 0, stream>>>(x, Wr, tp, (float*)ws);
  float* rw = (float*)ws;

  if (ws_size >= FULL) {
    size_t off = SZ_RW;
    short* xb  = (short*)(ws + off); off += SZ_XB;
    short* WTg = (short*)(ws + off); off += 8 * SZ_MAT;
    short* WTu = (short*)(ws + off); off += 8 * SZ_MAT;
    short* WdT = (short*)(ws + off); off += 8 * SZ_MAT;   // [2048][16384]
    short* h   = (short*)(ws + off);                      // [4096][16384]

    cvt_x_kernel<<<4096, 256, 0, stream>>>(x, xb);
    transpose_cvt_kernel<<<dim3(64, 64, 24), dim3(32, 8), 0, stream>>>(
        Wg, Wu, Wd, WTg, WTu, WdT, 8);
    fused_gu_kernel<<<dim3(16, 32, 8), 256, 0, stream>>>(
        xb, WTg, WTu, h, rw, 0, 16384, 2048);
    down_kernel<<<dim3(16, 32), 256, 0, stream>>>(h, WdT, out, 16384, 0);
  } else {
    size_t off = SZ_RW;
    short* xb  = (short*)(ws + off); off += SZ_XB;
    short* WTg = (short*)(ws + off); off += SZ_MAT;
    short* WTu = (short*)(ws + off); off += SZ_MAT;
    short* WdT = (short*)(ws + off); off += SZ_MAT;
    short* h   = (short*)(ws + off);                      // [4096][2048]

    cvt_x_kernel<<<4096, 256, 0, stream>>>(x, xb);
    for (int e = 0; e < 8; e++) {
      transpose_cvt_kernel<<<dim3(64, 64, 3), dim3(32, 8), 0, stream>>>(
          Wg + (size_t)e * MAT_ELEMS, Wu + (size_t)e * MAT_ELEMS,
          Wd + (size_t)e * MAT_ELEMS, WTg, WTu, WdT, 1);
      fused_gu_kernel<<<dim3(16, 32, 1), 256, 0, stream>>>(
          xb, WTg, WTu, h, rw, e, 2048, 0);
      down_kernel<<<dim3(16, 32), 256, 0, stream>>>(h, WdT, out, 2048, e > 0);
    }
  }
}

// Round 3
// 1146.056 us; speedup vs baseline: 1.6260x; 1.1437x over previous
//
#include <hip/hip_runtime.h>
#include <hip/hip_bf16.h>
#include <math.h>

// GoldenMoE: B=2,T=2048,D=2048,E=8,F=2048.
// Round 3: 256x256 tile, BK=32, 8 waves, 4-slot LDS ring, counted vmcnt(4),
// raw s_barrier, setprio, corrected XOR swizzle (chunk ^= (row>>1)&3),
// gate/up interleaved into one B' panel, split-K down GEMM.

#define E_NUM 8
#define BT_NUM 4096
#define MAT_ELEMS ((size_t)2048 * 2048)

typedef short short8 __attribute__((ext_vector_type(8)));
typedef float f32x4 __attribute__((ext_vector_type(4)));

__device__ __forceinline__ short f2bf(float f) {
  __hip_bfloat16 h = __float2bfloat16(f);
  return __builtin_bit_cast(short, h);
}

#define GLOAD_LDS(gptr, lptr) \
  __builtin_amdgcn_global_load_lds( \
      (const __attribute__((address_space(1))) unsigned int*)(gptr), \
      (__attribute__((address_space(3))) unsigned int*)(lptr), 16, 0, 0)

// ---------------- router ----------------
__global__ __launch_bounds__(256) void router_kernel(
    const float* __restrict__ x, const float* __restrict__ Wr,
    const float* __restrict__ temp, float* __restrict__ rw)
{
  const int bt = blockIdx.x;
  const int tid = threadIdx.x;
  const float* xp = x + (size_t)bt * 2048;
  float acc[E_NUM];
#pragma unroll
  for (int e = 0; e < E_NUM; e++) acc[e] = 0.f;
  for (int d = tid; d < 2048; d += 256) {
    float xv = xp[d];
    const float* wr = Wr + (size_t)d * E_NUM;
#pragma unroll
    for (int e = 0; e < E_NUM; e++) acc[e] += xv * wr[e];
  }
#pragma unroll
  for (int e = 0; e < E_NUM; e++) {
    float v = acc[e];
#pragma unroll
    for (int off = 32; off > 0; off >>= 1) v += __shfl_down(v, off, 64);
    acc[e] = v;
  }
  __shared__ float part[4][E_NUM];
  const int wid = tid >> 6, lane = tid & 63;
  if (lane == 0) {
#pragma unroll
    for (int e = 0; e < E_NUM; e++) part[wid][e] = acc[e];
  }
  __syncthreads();
  if (tid == 0) {
    const float t = temp[0];
    float wz[E_NUM], fb[E_NUM];
    float wsum = 0.f;
#pragma unroll
    for (int e = 0; e < E_NUM; e++) {
      float l = part[0][e] + part[1][e] + part[2][e] + part[3][e];
      float ih = 1.f / (1.f + expf(-l / t));
      float ds = fabsf(ih - 0.36787944117144233f);
      float in_zone = (ih >= 0.21231792754821915f && ih <= 0.5f) ? 1.f : 0.f;
      wz[e] = expf(-ds / 0.1f) * in_zone;
      wsum += wz[e];
      fb[e] = expf(-ds / 0.3f);
    }
    float w[E_NUM];
    if (wsum < 1e-8f) {
      int i1 = 0;
#pragma unroll
      for (int e = 1; e < E_NUM; e++) if (fb[e] > fb[i1]) i1 = e;
      int i2 = -1;
#pragma unroll
      for (int e = 0; e < E_NUM; e++) if (e != i1 && (i2 < 0 || fb[e] > fb[i2])) i2 = e;
      float s = fmaxf(fb[i1] + fb[i2], 1e-8f);
#pragma unroll
      for (int e = 0; e < E_NUM; e++) w[e] = (e == i1 || e == i2) ? fb[e] / s : 0.f;
    } else {
#pragma unroll
      for (int e = 0; e < E_NUM; e++) w[e] = wz[e];
    }
    float s2 = 0.f;
#pragma unroll
    for (int e = 0; e < E_NUM; e++) s2 += w[e];
    s2 = fmaxf(s2, 1e-8f);
    float inv = 1.f / s2;
#pragma unroll
    for (int e = 0; e < E_NUM; e++) rw[(size_t)bt * E_NUM + e] = w[e] * inv;
  }
}

// ---------------- x f32 -> bf16 ----------------
__global__ __launch_bounds__(256) void cvt_x_kernel(
    const float* __restrict__ x, short* __restrict__ xb)
{
  const size_t base = ((size_t)blockIdx.x * 256 + threadIdx.x) * 8;
  f32x4 v0 = *(const f32x4*)(x + base);
  f32x4 v1 = *(const f32x4*)(x + base + 4);
  short8 p;
#pragma unroll
  for (int j = 0; j < 4; j++) { p[j] = f2bf(v0[j]); p[4 + j] = f2bf(v1[j]); }
  *(short8*)(xb + base) = p;
}

// ------------- transpose + f32->bf16 -------------
// which = z/nexp: 0 Wg, 1 Wu (interleaved into B' per expert), 2 Wd.
// B' row n' = (col>>6)*128 + which*64 + (col&63), stride 2048, per-expert block.
// WdT: row n = col, col e*2048 + k, stride nexp*2048.
__global__ __launch_bounds__(256) void transpose_cvt_kernel(
    const float* __restrict__ sg, const float* __restrict__ su, const float* __restrict__ sd,
    short* __restrict__ dgu, short* __restrict__ dd, int nexp)
{
  const int which = blockIdx.z / nexp, e = blockIdx.z % nexp;
  __shared__ float t[32][33];
  const int tx = threadIdx.x, ty = threadIdx.y;
  const int x0 = blockIdx.x * 32, y0 = blockIdx.y * 32;
  const float* s = (which == 0 ? sg : which == 1 ? su : sd) + (size_t)e * MAT_ELEMS;
#pragma unroll
  for (int i = ty; i < 32; i += 8) t[i][tx] = s[(size_t)(y0 + i) * 2048 + x0 + tx];
  __syncthreads();
  if (which < 2) {
    short* d = dgu + (size_t)e * (2 * MAT_ELEMS);
#pragma unroll
    for (int i = ty; i < 32; i += 8) {
      const int col = x0 + i;
      const int np = ((col >> 6) * 128) + which * 64 + (col & 63);
      d[(size_t)np * 2048 + y0 + tx] = f2bf(t[tx][i]);
    }
  } else {
#pragma unroll
    for (int i = ty; i < 32; i += 8)
      dd[(size_t)(x0 + i) * ((size_t)nexp * 2048) + (size_t)e * 2048 + y0 + tx] = f2bf(t[tx][i]);
  }
}

// ================= 256x256 GEMM core, BK=32, 8 waves, 4-slot ring =================
// A [*][ldA], B [*][ldB] bf16, K-contiguous rows. T = K/32 tiles.
// LDS slot = 256 rows x 32 shorts (64B rows, 4 x 16B chunks).
// Swizzle: physical chunk = logical ^ ((row>>1)&3), both sides.
__device__ __forceinline__ void gemm_core(
    const short* __restrict__ Ab, const int ldA,
    const short* __restrict__ Bb, const int ldB, const int T,
    short* As, short* Bs, f32x4 (&acc)[4][8])
{
  const int tid = threadIdx.x;
  const int w = tid >> 6, lane = tid & 63;
  const int wm = w >> 1, wn = w & 1;
  const int r = lane & 15, g4 = lane >> 4;

  // staging: thread covers physical row PR (within 128-row half), chunk tid&3
  const int PR = tid >> 2;
  const int lc = (tid & 3) ^ ((PR >> 1) & 3);
  const size_t aSrc = (size_t)PR * ldA + lc * 8;
  const size_t bSrc = (size_t)PR * ldB + lc * 8;
  const size_t aSrc1 = aSrc + (size_t)128 * ldA;
  const size_t bSrc1 = bSrc + (size_t)128 * ldB;
  const int ldsDst = w * 512;  // shorts, wave-uniform

  int offA[4], offB[8];
#pragma unroll
  for (int m = 0; m < 4; m++) {
    const int row = wm * 64 + m * 16 + r;
    offA[m] = row * 32 + ((g4 ^ ((row >> 1) & 3)) * 8);
  }
#pragma unroll
  for (int n = 0; n < 8; n++) {
    const int row = wn * 128 + n * 16 + r;
    offB[n] = row * 32 + ((g4 ^ ((row >> 1) & 3)) * 8);
  }

#pragma unroll
  for (int m = 0; m < 4; m++)
#pragma unroll
    for (int n = 0; n < 8; n++) acc[m][n] = (f32x4){0.f, 0.f, 0.f, 0.f};

  // prologue: stage K-tiles 0 and 1 (K0's 4 loads first -> vmcnt(4) lands K0)
#pragma unroll
  for (int t = 0; t < 2; t++) {
    GLOAD_LDS(Ab + aSrc + t * 32,  As + t * 8192 + ldsDst);
    GLOAD_LDS(Bb + bSrc + t * 32,  Bs + t * 8192 + ldsDst);
    GLOAD_LDS(Ab + aSrc1 + t * 32, As + t * 8192 + 4096 + ldsDst);
    GLOAD_LDS(Bb + bSrc1 + t * 32, Bs + t * 8192 + 4096 + ldsDst);
  }
  asm volatile("s_waitcnt vmcnt(4)" ::: "memory");
  __builtin_amdgcn_s_barrier();

  for (int t = 0; t < T; t++) {
    const int slot = t & 3;
    const bool st = (t + 2) < T;
    const int s2 = (t + 2) & 3;
    short8 a[4], b[8];
    // ---- phase A: reads + stage half0(t+2) ----
#pragma unroll
    for (int m = 0; m < 4; m++) a[m] = *(const short8*)(As + slot * 8192 + offA[m]);
#pragma unroll
    for (int n = 0; n < 4; n++) b[n] = *(const short8*)(Bs + slot * 8192 + offB[n]);
    if (st) {
      GLOAD_LDS(Ab + aSrc + (t + 2) * 32, As + s2 * 8192 + ldsDst);
      GLOAD_LDS(Bb + bSrc + (t + 2) * 32, Bs + s2 * 8192 + ldsDst);
    }
    __builtin_amdgcn_s_barrier();
    asm volatile("s_waitcnt lgkmcnt(0)" ::: "memory");
    __builtin_amdgcn_sched_barrier(0);
    __builtin_amdgcn_s_setprio(1);
#pragma unroll
    for (int m = 0; m < 4; m++)
#pragma unroll
      for (int n = 0; n < 4; n++)
        asm volatile("v_mfma_f32_16x16x32_bf16 %0, %1, %2, %0"
                     : "+v"(acc[m][n]) : "v"(a[m]), "v"(b[n]));
    __builtin_amdgcn_s_setprio(0);
    __builtin_amdgcn_sched_barrier(0);
    __builtin_amdgcn_s_barrier();
    // ---- phase B: reads + stage half1(t+2) ----
#pragma unroll
    for (int n = 4; n < 8; n++) b[n] = *(const short8*)(Bs + slot * 8192 + offB[n]);
    if (st) {
      GLOAD_LDS(Ab + aSrc1 + (t + 2) * 32, As + s2 * 8192 + 4096 + ldsDst);
      GLOAD_LDS(Bb + bSrc1 + (t + 2) * 32, Bs + s2 * 8192 + 4096 + ldsDst);
    }
    __builtin_amdgcn_s_barrier();
    asm volatile("s_waitcnt lgkmcnt(0)" ::: "memory");
    __builtin_amdgcn_sched_barrier(0);
    __builtin_amdgcn_s_setprio(1);
#pragma unroll
    for (int m = 0; m < 4; m++)
#pragma unroll
      for (int n = 4; n < 8; n++)
        asm volatile("v_mfma_f32_16x16x32_bf16 %0, %1, %2, %0"
                     : "+v"(acc[m][n]) : "v"(a[m]), "v"(b[n]));
    __builtin_amdgcn_s_setprio(0);
    __builtin_amdgcn_sched_barrier(0);
    // counted fence: t+1's 4 loads (issued during t-1) retired; t+2's 4 may fly
    if (st) asm volatile("s_waitcnt vmcnt(4)" ::: "memory");
    else    asm volatile("s_waitcnt vmcnt(0)" ::: "memory");
    __builtin_amdgcn_s_barrier();
  }
  __builtin_amdgcn_sched_barrier(0);
  asm volatile("s_nop 7\n\ts_nop 7" ::: "memory");
}

// ---------------- fused gate+up kernel ----------------
// B' interleaved: per-expert [4096][2048]; pairs of 128 rows = 64 gate + 64 up.
// h[row][e*2048 + (bx*2+wn)*64 + n4*16 + r] = silu(g)*u*rw   (BATCHED)
template<int BATCHED>
__global__ __launch_bounds__(512, 1) void fused_gu_kernel(
    const short* __restrict__ xb, const short* __restrict__ Bgu,
    short* __restrict__ h, const float* __restrict__ rw, int e_param)
{
  __shared__ short As[4 * 8192];
  __shared__ short Bs[4 * 8192];
  int bx, by, e;
  const short* Bp;
  long hstride, hcol0;
  if (BATCHED) {
    const int swz = (blockIdx.x & 7) * 256 + (blockIdx.x >> 3);
    e = swz >> 8;
    const int rem = swz & 255;
    by = rem >> 4; bx = rem & 15;
    Bp = Bgu + (size_t)e * (2 * MAT_ELEMS);
    hstride = 16384; hcol0 = (long)e * 2048;
  } else {
    const int swz = (blockIdx.x & 7) * 32 + (blockIdx.x >> 3);
    e = e_param;
    by = swz >> 4; bx = swz & 15;
    Bp = Bgu;
    hstride = 2048; hcol0 = 0;
  }
  const int m0 = by * 256, n0 = bx * 256;

  f32x4 acc[4][8];
  gemm_core(xb + (size_t)m0 * 2048, 2048, Bp + (size_t)n0 * 2048, 2048, 64, As, Bs, acc);

  const int tid = threadIdx.x;
  const int w = tid >> 6, lane = tid & 63;
  const int wm = w >> 1, wn = w & 1;
  const int r = lane & 15, g4 = lane >> 4;
#pragma unroll
  for (int m = 0; m < 4; m++) {
#pragma unroll
    for (int j = 0; j < 4; j++) {
      const int row = m0 + wm * 64 + m * 16 + g4 * 4 + j;
      const float wt = rw[(size_t)row * 8 + e];
#pragma unroll
      for (int n4 = 0; n4 < 4; n4++) {
        const float g = acc[m][n4][j];
        const float u = acc[m][n4 + 4][j];
        const float hv = (g / (1.f + __expf(-g))) * u * wt;
        const long pcol = (long)(bx * 2 + wn) * 64 + n4 * 16 + r;
        h[(size_t)row * hstride + hcol0 + pcol] = f2bf(hv);
      }
    }
  }
}

// ---------------- down kernel (split-K=2, f32 partials) ----------------
template<int BATCHED>
__global__ __launch_bounds__(512, 1) void down_kernel(
    const short* __restrict__ h, const short* __restrict__ WdT,
    float* __restrict__ part)
{
  __shared__ short As[4 * 8192];
  __shared__ short Bs[4 * 8192];
  const int swz = (blockIdx.x & 7) * 32 + (blockIdx.x >> 3);
  const int z = swz >> 7;
  const int rem = swz & 127;
  const int by = rem >> 3, bx = rem & 7;
  const int m0 = by * 256, n0 = bx * 256;
  const int ld = BATCHED ? 16384 : 2048;
  const int kz = BATCHED ? 8192 : 1024;
  const int T = kz / 32;

  f32x4 acc[4][8];
  gemm_core(h + (size_t)m0 * ld + (size_t)z * kz, ld,
            WdT + (size_t)n0 * ld + (size_t)z * kz, ld, T, As, Bs, acc);

  float* pz = part + (size_t)z * BT_NUM * 2048;
  const int tid = threadIdx.x;
  const int w = tid >> 6, lane = tid & 63;
  const int wm = w >> 1, wn = w & 1;
  const int r = lane & 15, g4 = lane >> 4;
#pragma unroll
  for (int m = 0; m < 4; m++) {
#pragma unroll
    for (int n = 0; n < 8; n++) {
      const int col = n0 + wn * 128 + n * 16 + r;
#pragma unroll
      for (int j = 0; j < 4; j++) {
        const int row = m0 + wm * 64 + m * 16 + g4 * 4 + j;
        pz[(size_t)row * 2048 + col] = acc[m][n][j];
      }
    }
  }
}

// ---------------- add partials ----------------
__global__ __launch_bounds__(256) void add2_kernel(
    const float* __restrict__ p0, const float* __restrict__ p1,
    float* __restrict__ out, int accum)
{
  const size_t i = ((size_t)blockIdx.x * 256 + threadIdx.x) * 4;
  f32x4 v = *(const f32x4*)(p0 + i) + *(const f32x4*)(p1 + i);
  if (accum) v += *(const f32x4*)(out + i);
  *(f32x4*)(out + i) = v;
}

extern "C" void kernel_launch(void* const* d_in, const int* in_sizes, int n_in,
                              void* d_out, int out_size, void* d_ws, size_t ws_size,
                              hipStream_t stream)
{
  const float* x  = (const float*)d_in[0];
  const float* Wg = (const float*)d_in[1];
  const float* Wu = (const float*)d_in[2];
  const float* Wd = (const float*)d_in[3];
  const float* Wr = (const float*)d_in[4];
  const float* tp = (const float*)d_in[5];
  float* out = (float*)d_out;

  char* ws = (char*)d_ws;
  const size_t SZ_RW = (size_t)BT_NUM * 8 * 4;        // 128 KiB
  const size_t SZ_XB = (size_t)BT_NUM * 2048 * 2;     // 16 MiB
  const size_t SZ_BGU_E = 2 * MAT_ELEMS * 2;          // 16 MiB per expert
  const size_t SZ_PART = (size_t)2 * BT_NUM * 2048 * 4;  // 64 MiB

  const size_t FULL = SZ_RW + SZ_XB + 8 * SZ_BGU_E
                    + (size_t)2048 * 16384 * 2        // WdT 64 MiB
                    + (size_t)BT_NUM * 16384 * 2;     // h 128 MiB

  float* rw = (float*)ws;
  router_kernel<<<BT_NUM, 256, 0, stream>>>(x, Wr, tp, rw);

  if (ws_size >= FULL) {
    size_t off = SZ_RW;
    short* xb  = (short*)(ws + off); off += SZ_XB;
    short* Bgu = (short*)(ws + off); off += 8 * SZ_BGU_E;   // 128 MiB
    short* WdT = (short*)(ws + off); off += (size_t)2048 * 16384 * 2;
    short* h   = (short*)(ws + off);
    float* part = (float*)Bgu;   // reuse B' region after fused_gu (64 <= 128 MiB)

    cvt_x_kernel<<<4096, 256, 0, stream>>>(x, xb);
    transpose_cvt_kernel<<<dim3(64, 64, 24), dim3(32, 8), 0, stream>>>(
        Wg, Wu, Wd, Bgu, WdT, 8);
    fused_gu_kernel<1><<<2048, 512, 0, stream>>>(xb, Bgu, h, rw, 0);
    down_kernel<1><<<256, 512, 0, stream>>>(h, WdT, part);
    add2_kernel<<<8192, 256, 0, stream>>>(part, part + (size_t)BT_NUM * 2048, out, 0);
  } else {
    size_t off = SZ_RW;
    short* xb  = (short*)(ws + off); off += SZ_XB;
    short* Bgu = (short*)(ws + off); off += SZ_BGU_E;
    short* WdT = (short*)(ws + off); off += MAT_ELEMS * 2;
    short* h   = (short*)(ws + off); off += (size_t)BT_NUM * 2048 * 2;
    float* part = (float*)(ws + off);

    cvt_x_kernel<<<4096, 256, 0, stream>>>(x, xb);
    for (int e = 0; e < 8; e++) {
      transpose_cvt_kernel<<<dim3(64, 64, 3), dim3(32, 8), 0, stream>>>(
          Wg + (size_t)e * MAT_ELEMS, Wu + (size_t)e * MAT_ELEMS,
          Wd + (size_t)e * MAT_ELEMS, Bgu, WdT, 1);
      fused_gu_kernel<0><<<256, 512, 0, stream>>>(xb, Bgu, h, rw, e);
      down_kernel<0><<<256, 512, 0, stream>>>(h, WdT, part);
      add2_kernel<<<8192, 256, 0, stream>>>(part, part + (size_t)BT_NUM * 2048, out, e > 0);
    }
  }
}

// Round 4
// 1027.809 us; speedup vs baseline: 1.8131x; 1.1150x over previous
//
#include <hip/hip_runtime.h>
#include <hip/hip_bf16.h>
#include <math.h>

// GoldenMoE: B=2,T=2048,D=2048,E=8,F=2048.
// Round 4: counted-lgkmcnt ladder, 1 barrier per K-tile (was 4), 4-slot ring,
// counted vmcnt(4), zero-conflict chunk swizzle (chunk ^= (row>>1)&3).

#define E_NUM 8
#define BT_NUM 4096
#define MAT_ELEMS ((size_t)2048 * 2048)

typedef short short8 __attribute__((ext_vector_type(8)));
typedef float f32x4 __attribute__((ext_vector_type(4)));

__device__ __forceinline__ short f2bf(float f) {
  __hip_bfloat16 h = __float2bfloat16(f);
  return __builtin_bit_cast(short, h);
}

#define GLOAD_LDS(gptr, lptr) \
  __builtin_amdgcn_global_load_lds( \
      (const __attribute__((address_space(1))) unsigned int*)(gptr), \
      (__attribute__((address_space(3))) unsigned int*)(lptr), 16, 0, 0)

#define LDS_OFF(p) ((unsigned)(size_t)(__attribute__((address_space(3))) const short*)(p))

#define DS_READ_B128(d, a) \
  asm volatile("ds_read_b128 %0, %1" : "=v"(d) : "v"(a))

#define LGKM(n) do { \
  asm volatile("s_waitcnt lgkmcnt(" #n ")" ::: "memory"); \
  __builtin_amdgcn_sched_barrier(0); \
} while (0)

// ---------------- router ----------------
__global__ __launch_bounds__(256) void router_kernel(
    const float* __restrict__ x, const float* __restrict__ Wr,
    const float* __restrict__ temp, float* __restrict__ rw)
{
  const int bt = blockIdx.x;
  const int tid = threadIdx.x;
  const float* xp = x + (size_t)bt * 2048;
  float acc[E_NUM];
#pragma unroll
  for (int e = 0; e < E_NUM; e++) acc[e] = 0.f;
  for (int d = tid; d < 2048; d += 256) {
    float xv = xp[d];
    const float* wr = Wr + (size_t)d * E_NUM;
#pragma unroll
    for (int e = 0; e < E_NUM; e++) acc[e] += xv * wr[e];
  }
#pragma unroll
  for (int e = 0; e < E_NUM; e++) {
    float v = acc[e];
#pragma unroll
    for (int off = 32; off > 0; off >>= 1) v += __shfl_down(v, off, 64);
    acc[e] = v;
  }
  __shared__ float part[4][E_NUM];
  const int wid = tid >> 6, lane = tid & 63;
  if (lane == 0) {
#pragma unroll
    for (int e = 0; e < E_NUM; e++) part[wid][e] = acc[e];
  }
  __syncthreads();
  if (tid == 0) {
    const float t = temp[0];
    float wz[E_NUM], fb[E_NUM];
    float wsum = 0.f;
#pragma unroll
    for (int e = 0; e < E_NUM; e++) {
      float l = part[0][e] + part[1][e] + part[2][e] + part[3][e];
      float ih = 1.f / (1.f + expf(-l / t));
      float ds = fabsf(ih - 0.36787944117144233f);
      float in_zone = (ih >= 0.21231792754821915f && ih <= 0.5f) ? 1.f : 0.f;
      wz[e] = expf(-ds / 0.1f) * in_zone;
      wsum += wz[e];
      fb[e] = expf(-ds / 0.3f);
    }
    float w[E_NUM];
    if (wsum < 1e-8f) {
      int i1 = 0;
#pragma unroll
      for (int e = 1; e < E_NUM; e++) if (fb[e] > fb[i1]) i1 = e;
      int i2 = -1;
#pragma unroll
      for (int e = 0; e < E_NUM; e++) if (e != i1 && (i2 < 0 || fb[e] > fb[i2])) i2 = e;
      float s = fmaxf(fb[i1] + fb[i2], 1e-8f);
#pragma unroll
      for (int e = 0; e < E_NUM; e++) w[e] = (e == i1 || e == i2) ? fb[e] / s : 0.f;
    } else {
#pragma unroll
      for (int e = 0; e < E_NUM; e++) w[e] = wz[e];
    }
    float s2 = 0.f;
#pragma unroll
    for (int e = 0; e < E_NUM; e++) s2 += w[e];
    s2 = fmaxf(s2, 1e-8f);
    float inv = 1.f / s2;
#pragma unroll
    for (int e = 0; e < E_NUM; e++) rw[(size_t)bt * E_NUM + e] = w[e] * inv;
  }
}

// ---------------- x f32 -> bf16 ----------------
__global__ __launch_bounds__(256) void cvt_x_kernel(
    const float* __restrict__ x, short* __restrict__ xb)
{
  const size_t base = ((size_t)blockIdx.x * 256 + threadIdx.x) * 8;
  f32x4 v0 = *(const f32x4*)(x + base);
  f32x4 v1 = *(const f32x4*)(x + base + 4);
  short8 p;
#pragma unroll
  for (int j = 0; j < 4; j++) { p[j] = f2bf(v0[j]); p[4 + j] = f2bf(v1[j]); }
  *(short8*)(xb + base) = p;
}

// ------------- transpose + f32->bf16 -------------
__global__ __launch_bounds__(256) void transpose_cvt_kernel(
    const float* __restrict__ sg, const float* __restrict__ su, const float* __restrict__ sd,
    short* __restrict__ dgu, short* __restrict__ dd, int nexp)
{
  const int which = blockIdx.z / nexp, e = blockIdx.z % nexp;
  __shared__ float t[32][33];
  const int tx = threadIdx.x, ty = threadIdx.y;
  const int x0 = blockIdx.x * 32, y0 = blockIdx.y * 32;
  const float* s = (which == 0 ? sg : which == 1 ? su : sd) + (size_t)e * MAT_ELEMS;
#pragma unroll
  for (int i = ty; i < 32; i += 8) t[i][tx] = s[(size_t)(y0 + i) * 2048 + x0 + tx];
  __syncthreads();
  if (which < 2) {
    short* d = dgu + (size_t)e * (2 * MAT_ELEMS);
#pragma unroll
    for (int i = ty; i < 32; i += 8) {
      const int col = x0 + i;
      const int np = ((col >> 6) * 128) + which * 64 + (col & 63);
      d[(size_t)np * 2048 + y0 + tx] = f2bf(t[tx][i]);
    }
  } else {
#pragma unroll
    for (int i = ty; i < 32; i += 8)
      dd[(size_t)(x0 + i) * ((size_t)nexp * 2048) + (size_t)e * 2048 + y0 + tx] = f2bf(t[tx][i]);
  }
}

// ================= 256x256 GEMM core, BK=32, 8 waves, 4-slot ring =================
// Counted-lgkm ladder: 12 ordered ds_read_b128, MFMA clusters gated by lgkmcnt(N).
// One s_barrier + one counted vmcnt per K-tile.
__device__ __forceinline__ void gemm_core(
    const short* __restrict__ Ab, const int ldA,
    const short* __restrict__ Bb, const int ldB, const int T,
    short* As, short* Bs, f32x4 (&acc)[4][8])
{
  const int tid = threadIdx.x;
  const int w = tid >> 6, lane = tid & 63;
  const int wm = w >> 1, wn = w & 1;
  const int r = lane & 15, g4 = lane >> 4;

  // staging source (inverse-swizzled global address)
  const int PR = tid >> 2;
  const int lc = (tid & 3) ^ ((PR >> 1) & 3);
  const size_t aSrc = (size_t)PR * ldA + lc * 8;
  const size_t bSrc = (size_t)PR * ldB + lc * 8;
  const size_t aSrc1 = aSrc + (size_t)128 * ldA;
  const size_t bSrc1 = bSrc + (size_t)128 * ldB;
  const int ldsDst = w * 512;  // shorts, wave-uniform

  // fragment LDS byte addresses (slot-relative)
  const unsigned baseA = LDS_OFF(As);
  const unsigned baseB = LDS_OFF(Bs);
  unsigned adA[4], adB[8];
#pragma unroll
  for (int m = 0; m < 4; m++) {
    const int row = wm * 64 + m * 16 + r;
    adA[m] = baseA + (unsigned)(row * 32 + ((g4 ^ ((row >> 1) & 3)) * 8)) * 2u;
  }
#pragma unroll
  for (int n = 0; n < 8; n++) {
    const int row = wn * 128 + n * 16 + r;
    adB[n] = baseB + (unsigned)(row * 32 + ((g4 ^ ((row >> 1) & 3)) * 8)) * 2u;
  }

#pragma unroll
  for (int m = 0; m < 4; m++)
#pragma unroll
    for (int n = 0; n < 8; n++) acc[m][n] = (f32x4){0.f, 0.f, 0.f, 0.f};

  // prologue: stage K-tiles 0 and 1
#pragma unroll
  for (int t = 0; t < 2; t++) {
    GLOAD_LDS(Ab + aSrc + t * 32,  As + t * 8192 + ldsDst);
    GLOAD_LDS(Bb + bSrc + t * 32,  Bs + t * 8192 + ldsDst);
    GLOAD_LDS(Ab + aSrc1 + t * 32, As + t * 8192 + 4096 + ldsDst);
    GLOAD_LDS(Bb + bSrc1 + t * 32, Bs + t * 8192 + 4096 + ldsDst);
  }
  asm volatile("s_waitcnt lgkmcnt(0)" ::: "memory");   // drain any prologue SMEM
  asm volatile("s_waitcnt vmcnt(4)" ::: "memory");
  __builtin_amdgcn_s_barrier();

#define MFMA4(n) do { \
  asm volatile("v_mfma_f32_16x16x32_bf16 %0, %1, %2, %0" : "+v"(acc[0][n]) : "v"(a[0]), "v"(b[n])); \
  asm volatile("v_mfma_f32_16x16x32_bf16 %0, %1, %2, %0" : "+v"(acc[1][n]) : "v"(a[1]), "v"(b[n])); \
  asm volatile("v_mfma_f32_16x16x32_bf16 %0, %1, %2, %0" : "+v"(acc[2][n]) : "v"(a[2]), "v"(b[n])); \
  asm volatile("v_mfma_f32_16x16x32_bf16 %0, %1, %2, %0" : "+v"(acc[3][n]) : "v"(a[3]), "v"(b[n])); \
} while (0)

  for (int t = 0; t < T; ++t) {
    const unsigned sb = (unsigned)(t & 3) * 16384u;
    const bool st = (t + 2) < T;
    const int s2 = (t + 2) & 3;
    short8 a[4], b[8];
    // 12 ordered ds_reads (slot t)
    DS_READ_B128(a[0], adA[0] + sb);
    DS_READ_B128(a[1], adA[1] + sb);
    DS_READ_B128(a[2], adA[2] + sb);
    DS_READ_B128(a[3], adA[3] + sb);
    DS_READ_B128(b[0], adB[0] + sb);
    DS_READ_B128(b[1], adB[1] + sb);
    DS_READ_B128(b[2], adB[2] + sb);
    DS_READ_B128(b[3], adB[3] + sb);
    DS_READ_B128(b[4], adB[4] + sb);
    DS_READ_B128(b[5], adB[5] + sb);
    DS_READ_B128(b[6], adB[6] + sb);
    DS_READ_B128(b[7], adB[7] + sb);
    // prefetch slot t+2
    if (st) {
      GLOAD_LDS(Ab + aSrc + (t + 2) * 32,  As + s2 * 8192 + ldsDst);
      GLOAD_LDS(Bb + bSrc + (t + 2) * 32,  Bs + s2 * 8192 + ldsDst);
      GLOAD_LDS(Ab + aSrc1 + (t + 2) * 32, As + s2 * 8192 + 4096 + ldsDst);
      GLOAD_LDS(Bb + bSrc1 + (t + 2) * 32, Bs + s2 * 8192 + 4096 + ldsDst);
    }
    // counted ladder: cluster n fires when a0-3 + b0..bn have returned
    __builtin_amdgcn_s_setprio(1);
    LGKM(7); MFMA4(0);
    LGKM(6); MFMA4(1);
    LGKM(5); MFMA4(2);
    LGKM(4); MFMA4(3);
    LGKM(3); MFMA4(4);
    LGKM(2); MFMA4(5);
    LGKM(1); MFMA4(6);
    LGKM(0); MFMA4(7);
    __builtin_amdgcn_s_setprio(0);
    if (st) asm volatile("s_waitcnt vmcnt(4)" ::: "memory");
    else    asm volatile("s_waitcnt vmcnt(0)" ::: "memory");
    __builtin_amdgcn_s_barrier();
  }
#undef MFMA4
  __builtin_amdgcn_sched_barrier(0);
  asm volatile("s_nop 7\n\ts_nop 7" ::: "memory");
}

// ---------------- fused gate+up kernel ----------------
template<int BATCHED>
__global__ __launch_bounds__(512, 1) void fused_gu_kernel(
    const short* __restrict__ xb, const short* __restrict__ Bgu,
    short* __restrict__ h, const float* __restrict__ rw, int e_param)
{
  __shared__ short As[4 * 8192];
  __shared__ short Bs[4 * 8192];
  int bx, by, e;
  const short* Bp;
  long hstride, hcol0;
  if (BATCHED) {
    const int swz = (blockIdx.x & 7) * 256 + (blockIdx.x >> 3);
    e = swz >> 8;
    const int rem = swz & 255;
    by = rem >> 4; bx = rem & 15;
    Bp = Bgu + (size_t)e * (2 * MAT_ELEMS);
    hstride = 16384; hcol0 = (long)e * 2048;
  } else {
    const int swz = (blockIdx.x & 7) * 32 + (blockIdx.x >> 3);
    e = e_param;
    by = swz >> 4; bx = swz & 15;
    Bp = Bgu;
    hstride = 2048; hcol0 = 0;
  }
  const int m0 = by * 256, n0 = bx * 256;

  f32x4 acc[4][8];
  gemm_core(xb + (size_t)m0 * 2048, 2048, Bp + (size_t)n0 * 2048, 2048, 64, As, Bs, acc);

  const int tid = threadIdx.x;
  const int w = tid >> 6, lane = tid & 63;
  const int wm = w >> 1, wn = w & 1;
  const int r = lane & 15, g4 = lane >> 4;
#pragma unroll
  for (int m = 0; m < 4; m++) {
#pragma unroll
    for (int j = 0; j < 4; j++) {
      const int row = m0 + wm * 64 + m * 16 + g4 * 4 + j;
      const float wt = rw[(size_t)row * 8 + e];
#pragma unroll
      for (int n4 = 0; n4 < 4; n4++) {
        const float g = acc[m][n4][j];
        const float u = acc[m][n4 + 4][j];
        const float hv = (g / (1.f + __expf(-g))) * u * wt;
        const long pcol = (long)(bx * 2 + wn) * 64 + n4 * 16 + r;
        h[(size_t)row * hstride + hcol0 + pcol] = f2bf(hv);
      }
    }
  }
}

// ---------------- down kernel (split-K=2, f32 partials) ----------------
template<int BATCHED>
__global__ __launch_bounds__(512, 1) void down_kernel(
    const short* __restrict__ h, const short* __restrict__ WdT,
    float* __restrict__ part)
{
  __shared__ short As[4 * 8192];
  __shared__ short Bs[4 * 8192];
  const int swz = (blockIdx.x & 7) * 32 + (blockIdx.x >> 3);
  const int z = swz >> 7;
  const int rem = swz & 127;
  const int by = rem >> 3, bx = rem & 7;
  const int m0 = by * 256, n0 = bx * 256;
  const int ld = BATCHED ? 16384 : 2048;
  const int kz = BATCHED ? 8192 : 1024;
  const int T = kz / 32;

  f32x4 acc[4][8];
  gemm_core(h + (size_t)m0 * ld + (size_t)z * kz, ld,
            WdT + (size_t)n0 * ld + (size_t)z * kz, ld, T, As, Bs, acc);

  float* pz = part + (size_t)z * BT_NUM * 2048;
  const int tid = threadIdx.x;
  const int w = tid >> 6, lane = tid & 63;
  const int wm = w >> 1, wn = w & 1;
  const int r = lane & 15, g4 = lane >> 4;
#pragma unroll
  for (int m = 0; m < 4; m++) {
#pragma unroll
    for (int n = 0; n < 8; n++) {
      const int col = n0 + wn * 128 + n * 16 + r;
#pragma unroll
      for (int j = 0; j < 4; j++) {
        const int row = m0 + wm * 64 + m * 16 + g4 * 4 + j;
        pz[(size_t)row * 2048 + col] = acc[m][n][j];
      }
    }
  }
}

// ---------------- add partials ----------------
__global__ __launch_bounds__(256) void add2_kernel(
    const float* __restrict__ p0, const float* __restrict__ p1,
    float* __restrict__ out, int accum)
{
  const size_t i = ((size_t)blockIdx.x * 256 + threadIdx.x) * 4;
  f32x4 v = *(const f32x4*)(p0 + i) + *(const f32x4*)(p1 + i);
  if (accum) v += *(const f32x4*)(out + i);
  *(f32x4*)(out + i) = v;
}

extern "C" void kernel_launch(void* const* d_in, const int* in_sizes, int n_in,
                              void* d_out, int out_size, void* d_ws, size_t ws_size,
                              hipStream_t stream)
{
  const float* x  = (const float*)d_in[0];
  const float* Wg = (const float*)d_in[1];
  const float* Wu = (const float*)d_in[2];
  const float* Wd = (const float*)d_in[3];
  const float* Wr = (const float*)d_in[4];
  const float* tp = (const float*)d_in[5];
  float* out = (float*)d_out;

  char* ws = (char*)d_ws;
  const size_t SZ_RW = (size_t)BT_NUM * 8 * 4;
  const size_t SZ_XB = (size_t)BT_NUM * 2048 * 2;
  const size_t SZ_BGU_E = 2 * MAT_ELEMS * 2;

  const size_t FULL = SZ_RW + SZ_XB + 8 * SZ_BGU_E
                    + (size_t)2048 * 16384 * 2
                    + (size_t)BT_NUM * 16384 * 2;

  float* rw = (float*)ws;
  router_kernel<<<BT_NUM, 256, 0, stream>>>(x, Wr, tp, rw);

  if (ws_size >= FULL) {
    size_t off = SZ_RW;
    short* xb  = (short*)(ws + off); off += SZ_XB;
    short* Bgu = (short*)(ws + off); off += 8 * SZ_BGU_E;
    short* WdT = (short*)(ws + off); off += (size_t)2048 * 16384 * 2;
    short* h   = (short*)(ws + off);
    float* part = (float*)Bgu;   // reuse B' region after fused_gu

    cvt_x_kernel<<<4096, 256, 0, stream>>>(x, xb);
    transpose_cvt_kernel<<<dim3(64, 64, 24), dim3(32, 8), 0, stream>>>(
        Wg, Wu, Wd, Bgu, WdT, 8);
    fused_gu_kernel<1><<<2048, 512, 0, stream>>>(xb, Bgu, h, rw, 0);
    down_kernel<1><<<256, 512, 0, stream>>>(h, WdT, part);
    add2_kernel<<<8192, 256, 0, stream>>>(part, part + (size_t)BT_NUM * 2048, out, 0);
  } else {
    size_t off = SZ_RW;
    short* xb  = (short*)(ws + off); off += SZ_XB;
    short* Bgu = (short*)(ws + off); off += SZ_BGU_E;
    short* WdT = (short*)(ws + off); off += MAT_ELEMS * 2;
    short* h   = (short*)(ws + off); off += (size_t)BT_NUM * 2048 * 2;
    float* part = (float*)(ws + off);

    cvt_x_kernel<<<4096, 256, 0, stream>>>(x, xb);
    for (int e = 0; e < 8; e++) {
      transpose_cvt_kernel<<<dim3(64, 64, 3), dim3(32, 8), 0, stream>>>(
          Wg + (size_t)e * MAT_ELEMS, Wu + (size_t)e * MAT_ELEMS,
          Wd + (size_t)e * MAT_ELEMS, Bgu, WdT, 1);
      fused_gu_kernel<0><<<256, 512, 0, stream>>>(xb, Bgu, h, rw, e);
      down_kernel<0><<<256, 512, 0, stream>>>(h, WdT, part);
      add2_kernel<<<8192, 256, 0, stream>>>(part, part + (size_t)BT_NUM * 2048, out, e > 0);
    }
  }
}

// Round 5
// 1019.346 us; speedup vs baseline: 1.8281x; 1.0083x over previous
//
#include <hip/hip_runtime.h>
#include <hip/hip_bf16.h>
#include <math.h>

// GoldenMoE: B=2,T=2048,D=2048,E=8,F=2048.
// Round 5: register double-buffered K-pipeline — ds_reads of tile t+1 overlap
// MFMAs of tile t (single lgkmcnt(12) gate); 4-slot ring, distance-3 prefetch,
// one barrier + counted vmcnt(4) per tile; zero-conflict chunk swizzle.

#define E_NUM 8
#define BT_NUM 4096
#define MAT_ELEMS ((size_t)2048 * 2048)

typedef short short8 __attribute__((ext_vector_type(8)));
typedef float f32x4 __attribute__((ext_vector_type(4)));

__device__ __forceinline__ short f2bf(float f) {
  __hip_bfloat16 h = __float2bfloat16(f);
  return __builtin_bit_cast(short, h);
}

#define GLOAD_LDS(gptr, lptr) \
  __builtin_amdgcn_global_load_lds( \
      (const __attribute__((address_space(1))) unsigned int*)(gptr), \
      (__attribute__((address_space(3))) unsigned int*)(lptr), 16, 0, 0)

#define LDS_OFF(p) ((unsigned)(size_t)(__attribute__((address_space(3))) const short*)(p))

#define DS_READ_B128(d, a) \
  asm volatile("ds_read_b128 %0, %1" : "=v"(d) : "v"(a))

#define LGKM(n) do { \
  asm volatile("s_waitcnt lgkmcnt(" #n ")" ::: "memory"); \
  __builtin_amdgcn_sched_barrier(0); \
} while (0)

// ---------------- router ----------------
__global__ __launch_bounds__(256) void router_kernel(
    const float* __restrict__ x, const float* __restrict__ Wr,
    const float* __restrict__ temp, float* __restrict__ rw)
{
  const int bt = blockIdx.x;
  const int tid = threadIdx.x;
  const float* xp = x + (size_t)bt * 2048;
  float acc[E_NUM];
#pragma unroll
  for (int e = 0; e < E_NUM; e++) acc[e] = 0.f;
  for (int d = tid; d < 2048; d += 256) {
    float xv = xp[d];
    const float* wr = Wr + (size_t)d * E_NUM;
#pragma unroll
    for (int e = 0; e < E_NUM; e++) acc[e] += xv * wr[e];
  }
#pragma unroll
  for (int e = 0; e < E_NUM; e++) {
    float v = acc[e];
#pragma unroll
    for (int off = 32; off > 0; off >>= 1) v += __shfl_down(v, off, 64);
    acc[e] = v;
  }
  __shared__ float part[4][E_NUM];
  const int wid = tid >> 6, lane = tid & 63;
  if (lane == 0) {
#pragma unroll
    for (int e = 0; e < E_NUM; e++) part[wid][e] = acc[e];
  }
  __syncthreads();
  if (tid == 0) {
    const float t = temp[0];
    float wz[E_NUM], fb[E_NUM];
    float wsum = 0.f;
#pragma unroll
    for (int e = 0; e < E_NUM; e++) {
      float l = part[0][e] + part[1][e] + part[2][e] + part[3][e];
      float ih = 1.f / (1.f + expf(-l / t));
      float ds = fabsf(ih - 0.36787944117144233f);
      float in_zone = (ih >= 0.21231792754821915f && ih <= 0.5f) ? 1.f : 0.f;
      wz[e] = expf(-ds / 0.1f) * in_zone;
      wsum += wz[e];
      fb[e] = expf(-ds / 0.3f);
    }
    float w[E_NUM];
    if (wsum < 1e-8f) {
      int i1 = 0;
#pragma unroll
      for (int e = 1; e < E_NUM; e++) if (fb[e] > fb[i1]) i1 = e;
      int i2 = -1;
#pragma unroll
      for (int e = 0; e < E_NUM; e++) if (e != i1 && (i2 < 0 || fb[e] > fb[i2])) i2 = e;
      float s = fmaxf(fb[i1] + fb[i2], 1e-8f);
#pragma unroll
      for (int e = 0; e < E_NUM; e++) w[e] = (e == i1 || e == i2) ? fb[e] / s : 0.f;
    } else {
#pragma unroll
      for (int e = 0; e < E_NUM; e++) w[e] = wz[e];
    }
    float s2 = 0.f;
#pragma unroll
    for (int e = 0; e < E_NUM; e++) s2 += w[e];
    s2 = fmaxf(s2, 1e-8f);
    float inv = 1.f / s2;
#pragma unroll
    for (int e = 0; e < E_NUM; e++) rw[(size_t)bt * E_NUM + e] = w[e] * inv;
  }
}

// ---------------- x f32 -> bf16 ----------------
__global__ __launch_bounds__(256) void cvt_x_kernel(
    const float* __restrict__ x, short* __restrict__ xb)
{
  const size_t base = ((size_t)blockIdx.x * 256 + threadIdx.x) * 8;
  f32x4 v0 = *(const f32x4*)(x + base);
  f32x4 v1 = *(const f32x4*)(x + base + 4);
  short8 p;
#pragma unroll
  for (int j = 0; j < 4; j++) { p[j] = f2bf(v0[j]); p[4 + j] = f2bf(v1[j]); }
  *(short8*)(xb + base) = p;
}

// ------------- transpose + f32->bf16 -------------
__global__ __launch_bounds__(256) void transpose_cvt_kernel(
    const float* __restrict__ sg, const float* __restrict__ su, const float* __restrict__ sd,
    short* __restrict__ dgu, short* __restrict__ dd, int nexp)
{
  const int which = blockIdx.z / nexp, e = blockIdx.z % nexp;
  __shared__ float t[32][33];
  const int tx = threadIdx.x, ty = threadIdx.y;
  const int x0 = blockIdx.x * 32, y0 = blockIdx.y * 32;
  const float* s = (which == 0 ? sg : which == 1 ? su : sd) + (size_t)e * MAT_ELEMS;
#pragma unroll
  for (int i = ty; i < 32; i += 8) t[i][tx] = s[(size_t)(y0 + i) * 2048 + x0 + tx];
  __syncthreads();
  if (which < 2) {
    short* d = dgu + (size_t)e * (2 * MAT_ELEMS);
#pragma unroll
    for (int i = ty; i < 32; i += 8) {
      const int col = x0 + i;
      const int np = ((col >> 6) * 128) + which * 64 + (col & 63);
      d[(size_t)np * 2048 + y0 + tx] = f2bf(t[tx][i]);
    }
  } else {
#pragma unroll
    for (int i = ty; i < 32; i += 8)
      dd[(size_t)(x0 + i) * ((size_t)nexp * 2048) + (size_t)e * 2048 + y0 + tx] = f2bf(t[tx][i]);
  }
}

// ================= 256x256 GEMM core, BK=32, 8 waves =================
// 4-slot LDS ring, distance-3 gload prefetch, register double-buffered
// fragment reads: iter t reads slot t+1 into NXT regs while MFMAing CUR.
__device__ __forceinline__ void gemm_core(
    const short* __restrict__ Ab, const int ldA,
    const short* __restrict__ Bb, const int ldB, const int T,
    short* As, short* Bs, f32x4 (&acc)[4][8])
{
  const int tid = threadIdx.x;
  const int w = tid >> 6, lane = tid & 63;
  const int wm = w >> 1, wn = w & 1;
  const int r = lane & 15, g4 = lane >> 4;

  // staging source (inverse-swizzled global address)
  const int PR = tid >> 2;
  const int lc = (tid & 3) ^ ((PR >> 1) & 3);
  const size_t aSrc = (size_t)PR * ldA + lc * 8;
  const size_t bSrc = (size_t)PR * ldB + lc * 8;
  const size_t aSrc1 = aSrc + (size_t)128 * ldA;
  const size_t bSrc1 = bSrc + (size_t)128 * ldB;
  const int ldsDst = w * 512;  // shorts, wave-uniform

  // fragment LDS byte addresses (slot-relative)
  const unsigned baseA = LDS_OFF(As);
  const unsigned baseB = LDS_OFF(Bs);
  unsigned adA[4], adB[8];
#pragma unroll
  for (int m = 0; m < 4; m++) {
    const int row = wm * 64 + m * 16 + r;
    adA[m] = baseA + (unsigned)(row * 32 + ((g4 ^ ((row >> 1) & 3)) * 8)) * 2u;
  }
#pragma unroll
  for (int n = 0; n < 8; n++) {
    const int row = wn * 128 + n * 16 + r;
    adB[n] = baseB + (unsigned)(row * 32 + ((g4 ^ ((row >> 1) & 3)) * 8)) * 2u;
  }

#pragma unroll
  for (int m = 0; m < 4; m++)
#pragma unroll
    for (int n = 0; n < 8; n++) acc[m][n] = (f32x4){0.f, 0.f, 0.f, 0.f};

  // prologue: stage slots 0,1,2 (order matters for counted vmcnt)
#pragma unroll
  for (int t = 0; t < 3; t++) {
    GLOAD_LDS(Ab + aSrc + t * 32,  As + t * 8192 + ldsDst);
    GLOAD_LDS(Bb + bSrc + t * 32,  Bs + t * 8192 + ldsDst);
    GLOAD_LDS(Ab + aSrc1 + t * 32, As + t * 8192 + 4096 + ldsDst);
    GLOAD_LDS(Bb + bSrc1 + t * 32, Bs + t * 8192 + 4096 + ldsDst);
  }
  asm volatile("s_waitcnt vmcnt(4)" ::: "memory");  // slots 0 and 1 resident
  __builtin_amdgcn_s_barrier();

  short8 Xa[4], Xb[8], Ya[4], Yb[8];
  // preload slot 0 fragments (no wait here; first body's LGKM(12) covers it)
  DS_READ_B128(Xa[0], adA[0]);
  DS_READ_B128(Xa[1], adA[1]);
  DS_READ_B128(Xa[2], adA[2]);
  DS_READ_B128(Xa[3], adA[3]);
  DS_READ_B128(Xb[0], adB[0]);
  DS_READ_B128(Xb[1], adB[1]);
  DS_READ_B128(Xb[2], adB[2]);
  DS_READ_B128(Xb[3], adB[3]);
  DS_READ_B128(Xb[4], adB[4]);
  DS_READ_B128(Xb[5], adB[5]);
  DS_READ_B128(Xb[6], adB[6]);
  DS_READ_B128(Xb[7], adB[7]);

#define TILE_BODY(t, CA, CB, NA, NB) do { \
  const int tp1 = (t) + 1, tp3 = (t) + 3; \
  if (tp3 < T) { \
    const int s3 = tp3 & 3; \
    GLOAD_LDS(Ab + aSrc + (size_t)tp3 * 32,  As + s3 * 8192 + ldsDst); \
    GLOAD_LDS(Bb + bSrc + (size_t)tp3 * 32,  Bs + s3 * 8192 + ldsDst); \
    GLOAD_LDS(Ab + aSrc1 + (size_t)tp3 * 32, As + s3 * 8192 + 4096 + ldsDst); \
    GLOAD_LDS(Bb + bSrc1 + (size_t)tp3 * 32, Bs + s3 * 8192 + 4096 + ldsDst); \
  } \
  if (tp1 < T) { \
    const unsigned sb1 = (unsigned)(tp1 & 3) * 16384u; \
    DS_READ_B128(NA[0], adA[0] + sb1); \
    DS_READ_B128(NA[1], adA[1] + sb1); \
    DS_READ_B128(NA[2], adA[2] + sb1); \
    DS_READ_B128(NA[3], adA[3] + sb1); \
    DS_READ_B128(NB[0], adB[0] + sb1); \
    DS_READ_B128(NB[1], adB[1] + sb1); \
    DS_READ_B128(NB[2], adB[2] + sb1); \
    DS_READ_B128(NB[3], adB[3] + sb1); \
    DS_READ_B128(NB[4], adB[4] + sb1); \
    DS_READ_B128(NB[5], adB[5] + sb1); \
    DS_READ_B128(NB[6], adB[6] + sb1); \
    DS_READ_B128(NB[7], adB[7] + sb1); \
    LGKM(12); \
  } else { \
    LGKM(0); \
  } \
  __builtin_amdgcn_s_setprio(1); \
  _Pragma("unroll") \
  for (int mm = 0; mm < 4; mm++) \
    _Pragma("unroll") \
    for (int nn = 0; nn < 8; nn++) \
      asm volatile("v_mfma_f32_16x16x32_bf16 %0, %1, %2, %0" \
                   : "+v"(acc[mm][nn]) : "v"(CA[mm]), "v"(CB[nn])); \
  __builtin_amdgcn_s_setprio(0); \
  __builtin_amdgcn_sched_barrier(0); \
  if (tp3 < T) { asm volatile("s_waitcnt vmcnt(4)" ::: "memory"); } \
  else { asm volatile("s_waitcnt vmcnt(0)" ::: "memory"); } \
  __builtin_amdgcn_s_barrier(); \
} while (0)

  for (int t = 0; t < T; t += 2) {
    TILE_BODY(t, Xa, Xb, Ya, Yb);
    TILE_BODY(t + 1, Ya, Yb, Xa, Xb);
  }
#undef TILE_BODY
  __builtin_amdgcn_sched_barrier(0);
  asm volatile("s_nop 7\n\ts_nop 7" ::: "memory");
}

// ---------------- fused gate+up kernel ----------------
template<int BATCHED>
__global__ __launch_bounds__(512, 1) void fused_gu_kernel(
    const short* __restrict__ xb, const short* __restrict__ Bgu,
    short* __restrict__ h, const float* __restrict__ rw, int e_param)
{
  __shared__ short As[4 * 8192];
  __shared__ short Bs[4 * 8192];
  int bx, by, e;
  const short* Bp;
  long hstride, hcol0;
  if (BATCHED) {
    const int swz = (blockIdx.x & 7) * 256 + (blockIdx.x >> 3);
    e = swz >> 8;
    const int rem = swz & 255;
    by = rem >> 4; bx = rem & 15;
    Bp = Bgu + (size_t)e * (2 * MAT_ELEMS);
    hstride = 16384; hcol0 = (long)e * 2048;
  } else {
    const int swz = (blockIdx.x & 7) * 32 + (blockIdx.x >> 3);
    e = e_param;
    by = swz >> 4; bx = swz & 15;
    Bp = Bgu;
    hstride = 2048; hcol0 = 0;
  }
  const int m0 = by * 256, n0 = bx * 256;

  f32x4 acc[4][8];
  gemm_core(xb + (size_t)m0 * 2048, 2048, Bp + (size_t)n0 * 2048, 2048, 64, As, Bs, acc);

  const int tid = threadIdx.x;
  const int w = tid >> 6, lane = tid & 63;
  const int wm = w >> 1, wn = w & 1;
  const int r = lane & 15, g4 = lane >> 4;
#pragma unroll
  for (int m = 0; m < 4; m++) {
#pragma unroll
    for (int j = 0; j < 4; j++) {
      const int row = m0 + wm * 64 + m * 16 + g4 * 4 + j;
      const float wt = rw[(size_t)row * 8 + e];
#pragma unroll
      for (int n4 = 0; n4 < 4; n4++) {
        const float g = acc[m][n4][j];
        const float u = acc[m][n4 + 4][j];
        const float hv = (g / (1.f + __expf(-g))) * u * wt;
        const long pcol = (long)(bx * 2 + wn) * 64 + n4 * 16 + r;
        h[(size_t)row * hstride + hcol0 + pcol] = f2bf(hv);
      }
    }
  }
}

// ---------------- down kernel (split-K=2, f32 partials) ----------------
template<int BATCHED>
__global__ __launch_bounds__(512, 1) void down_kernel(
    const short* __restrict__ h, const short* __restrict__ WdT,
    float* __restrict__ part)
{
  __shared__ short As[4 * 8192];
  __shared__ short Bs[4 * 8192];
  const int swz = (blockIdx.x & 7) * 32 + (blockIdx.x >> 3);
  const int z = swz >> 7;
  const int rem = swz & 127;
  const int by = rem >> 3, bx = rem & 7;
  const int m0 = by * 256, n0 = bx * 256;
  const int ld = BATCHED ? 16384 : 2048;
  const int kz = BATCHED ? 8192 : 1024;
  const int T = kz / 32;

  f32x4 acc[4][8];
  gemm_core(h + (size_t)m0 * ld + (size_t)z * kz, ld,
            WdT + (size_t)n0 * ld + (size_t)z * kz, ld, T, As, Bs, acc);

  float* pz = part + (size_t)z * BT_NUM * 2048;
  const int tid = threadIdx.x;
  const int w = tid >> 6, lane = tid & 63;
  const int wm = w >> 1, wn = w & 1;
  const int r = lane & 15, g4 = lane >> 4;
#pragma unroll
  for (int m = 0; m < 4; m++) {
#pragma unroll
    for (int n = 0; n < 8; n++) {
      const int col = n0 + wn * 128 + n * 16 + r;
#pragma unroll
      for (int j = 0; j < 4; j++) {
        const int row = m0 + wm * 64 + m * 16 + g4 * 4 + j;
        pz[(size_t)row * 2048 + col] = acc[m][n][j];
      }
    }
  }
}

// ---------------- add partials ----------------
__global__ __launch_bounds__(256) void add2_kernel(
    const float* __restrict__ p0, const float* __restrict__ p1,
    float* __restrict__ out, int accum)
{
  const size_t i = ((size_t)blockIdx.x * 256 + threadIdx.x) * 4;
  f32x4 v = *(const f32x4*)(p0 + i) + *(const f32x4*)(p1 + i);
  if (accum) v += *(const f32x4*)(out + i);
  *(f32x4*)(out + i) = v;
}

extern "C" void kernel_launch(void* const* d_in, const int* in_sizes, int n_in,
                              void* d_out, int out_size, void* d_ws, size_t ws_size,
                              hipStream_t stream)
{
  const float* x  = (const float*)d_in[0];
  const float* Wg = (const float*)d_in[1];
  const float* Wu = (const float*)d_in[2];
  const float* Wd = (const float*)d_in[3];
  const float* Wr = (const float*)d_in[4];
  const float* tp = (const float*)d_in[5];
  float* out = (float*)d_out;

  char* ws = (char*)d_ws;
  const size_t SZ_RW = (size_t)BT_NUM * 8 * 4;
  const size_t SZ_XB = (size_t)BT_NUM * 2048 * 2;
  const size_t SZ_BGU_E = 2 * MAT_ELEMS * 2;

  const size_t FULL = SZ_RW + SZ_XB + 8 * SZ_BGU_E
                    + (size_t)2048 * 16384 * 2
                    + (size_t)BT_NUM * 16384 * 2;

  float* rw = (float*)ws;
  router_kernel<<<BT_NUM, 256, 0, stream>>>(x, Wr, tp, rw);

  if (ws_size >= FULL) {
    size_t off = SZ_RW;
    short* xb  = (short*)(ws + off); off += SZ_XB;
    short* Bgu = (short*)(ws + off); off += 8 * SZ_BGU_E;
    short* WdT = (short*)(ws + off); off += (size_t)2048 * 16384 * 2;
    short* h   = (short*)(ws + off);
    float* part = (float*)Bgu;   // reuse B' region after fused_gu

    cvt_x_kernel<<<4096, 256, 0, stream>>>(x, xb);
    transpose_cvt_kernel<<<dim3(64, 64, 24), dim3(32, 8), 0, stream>>>(
        Wg, Wu, Wd, Bgu, WdT, 8);
    fused_gu_kernel<1><<<2048, 512, 0, stream>>>(xb, Bgu, h, rw, 0);
    down_kernel<1><<<256, 512, 0, stream>>>(h, WdT, part);
    add2_kernel<<<8192, 256, 0, stream>>>(part, part + (size_t)BT_NUM * 2048, out, 0);
  } else {
    size_t off = SZ_RW;
    short* xb  = (short*)(ws + off); off += SZ_XB;
    short* Bgu = (short*)(ws + off); off += SZ_BGU_E;
    short* WdT = (short*)(ws + off); off += MAT_ELEMS * 2;
    short* h   = (short*)(ws + off); off += (size_t)BT_NUM * 2048 * 2;
    float* part = (float*)(ws + off);

    cvt_x_kernel<<<4096, 256, 0, stream>>>(x, xb);
    for (int e = 0; e < 8; e++) {
      transpose_cvt_kernel<<<dim3(64, 64, 3), dim3(32, 8), 0, stream>>>(
          Wg + (size_t)e * MAT_ELEMS, Wu + (size_t)e * MAT_ELEMS,
          Wd + (size_t)e * MAT_ELEMS, Bgu, WdT, 1);
      fused_gu_kernel<0><<<256, 512, 0, stream>>>(xb, Bgu, h, rw, e);
      down_kernel<0><<<256, 512, 0, stream>>>(h, WdT, part);
      add2_kernel<<<8192, 256, 0, stream>>>(part, part + (size_t)BT_NUM * 2048, out, e > 0);
    }
  }
}

// Round 6
// 894.682 us; speedup vs baseline: 2.0829x; 1.1393x over previous
//
#include <hip/hip_runtime.h>
#include <hip/hip_bf16.h>
#include <math.h>

// GoldenMoE: B=2,T=2048,D=2048,E=8,F=2048.
// Round 6: m201-style 8-phase 256x256 BK=64 template, 2-buffer LDS (128KiB),
// counted vmcnt(4) at phases 4/8 only, chunk-XOR swizzle (phys = log ^ (row&7)),
// gate/up interleaved at 32-col granularity (pair within one wave).

#define E_NUM 8
#define BT_NUM 4096
#define MAT_ELEMS ((size_t)2048 * 2048)

typedef short short8 __attribute__((ext_vector_type(8)));
typedef float f32x4 __attribute__((ext_vector_type(4)));

__device__ __forceinline__ short f2bf(float f) {
  __hip_bfloat16 h = __float2bfloat16(f);
  return __builtin_bit_cast(short, h);
}

#define GLOAD_LDS(gptr, lptr) \
  __builtin_amdgcn_global_load_lds( \
      (const __attribute__((address_space(1))) unsigned int*)(gptr), \
      (__attribute__((address_space(3))) unsigned int*)(lptr), 16, 0, 0)

#define LDS_OFF(p) ((unsigned)(size_t)(__attribute__((address_space(3))) const short*)(p))

#define DS_READ_B128(d, a) \
  asm volatile("ds_read_b128 %0, %1" : "=v"(d) : "v"(a))

#define BAR() __builtin_amdgcn_s_barrier()
#define LGKM0() do { \
  asm volatile("s_waitcnt lgkmcnt(0)" ::: "memory"); \
  __builtin_amdgcn_sched_barrier(0); \
} while (0)
#define VMC(n) asm volatile("s_waitcnt vmcnt(" #n ")" ::: "memory")

// ---------------- router ----------------
__global__ __launch_bounds__(256) void router_kernel(
    const float* __restrict__ x, const float* __restrict__ Wr,
    const float* __restrict__ temp, float* __restrict__ rw)
{
  const int bt = blockIdx.x;
  const int tid = threadIdx.x;
  const float* xp = x + (size_t)bt * 2048;
  float acc[E_NUM];
#pragma unroll
  for (int e = 0; e < E_NUM; e++) acc[e] = 0.f;
  for (int d = tid; d < 2048; d += 256) {
    float xv = xp[d];
    const float* wr = Wr + (size_t)d * E_NUM;
#pragma unroll
    for (int e = 0; e < E_NUM; e++) acc[e] += xv * wr[e];
  }
#pragma unroll
  for (int e = 0; e < E_NUM; e++) {
    float v = acc[e];
#pragma unroll
    for (int off = 32; off > 0; off >>= 1) v += __shfl_down(v, off, 64);
    acc[e] = v;
  }
  __shared__ float part[4][E_NUM];
  const int wid = tid >> 6, lane = tid & 63;
  if (lane == 0) {
#pragma unroll
    for (int e = 0; e < E_NUM; e++) part[wid][e] = acc[e];
  }
  __syncthreads();
  if (tid == 0) {
    const float t = temp[0];
    float wz[E_NUM], fb[E_NUM];
    float wsum = 0.f;
#pragma unroll
    for (int e = 0; e < E_NUM; e++) {
      float l = part[0][e] + part[1][e] + part[2][e] + part[3][e];
      float ih = 1.f / (1.f + expf(-l / t));
      float ds = fabsf(ih - 0.36787944117144233f);
      float in_zone = (ih >= 0.21231792754821915f && ih <= 0.5f) ? 1.f : 0.f;
      wz[e] = expf(-ds / 0.1f) * in_zone;
      wsum += wz[e];
      fb[e] = expf(-ds / 0.3f);
    }
    float w[E_NUM];
    if (wsum < 1e-8f) {
      int i1 = 0;
#pragma unroll
      for (int e = 1; e < E_NUM; e++) if (fb[e] > fb[i1]) i1 = e;
      int i2 = -1;
#pragma unroll
      for (int e = 0; e < E_NUM; e++) if (e != i1 && (i2 < 0 || fb[e] > fb[i2])) i2 = e;
      float s = fmaxf(fb[i1] + fb[i2], 1e-8f);
#pragma unroll
      for (int e = 0; e < E_NUM; e++) w[e] = (e == i1 || e == i2) ? fb[e] / s : 0.f;
    } else {
#pragma unroll
      for (int e = 0; e < E_NUM; e++) w[e] = wz[e];
    }
    float s2 = 0.f;
#pragma unroll
    for (int e = 0; e < E_NUM; e++) s2 += w[e];
    s2 = fmaxf(s2, 1e-8f);
    float inv = 1.f / s2;
#pragma unroll
    for (int e = 0; e < E_NUM; e++) rw[(size_t)bt * E_NUM + e] = w[e] * inv;
  }
}

// ---------------- x f32 -> bf16 ----------------
__global__ __launch_bounds__(256) void cvt_x_kernel(
    const float* __restrict__ x, short* __restrict__ xb)
{
  const size_t base = ((size_t)blockIdx.x * 256 + threadIdx.x) * 8;
  f32x4 v0 = *(const f32x4*)(x + base);
  f32x4 v1 = *(const f32x4*)(x + base + 4);
  short8 p;
#pragma unroll
  for (int j = 0; j < 4; j++) { p[j] = f2bf(v0[j]); p[4 + j] = f2bf(v1[j]); }
  *(short8*)(xb + base) = p;
}

// ------------- transpose + f32->bf16 -------------
// which 0:Wg 1:Wu -> B' rows np = (col>>5)*64 + which*32 + (col&31)  (32-col pairs)
// which 2:Wd -> WdT[n][e*2048+k], stride nexp*2048.
__global__ __launch_bounds__(256) void transpose_cvt_kernel(
    const float* __restrict__ sg, const float* __restrict__ su, const float* __restrict__ sd,
    short* __restrict__ dgu, short* __restrict__ dd, int nexp)
{
  const int which = blockIdx.z / nexp, e = blockIdx.z % nexp;
  __shared__ float t[32][33];
  const int tx = threadIdx.x, ty = threadIdx.y;
  const int x0 = blockIdx.x * 32, y0 = blockIdx.y * 32;
  const float* s = (which == 0 ? sg : which == 1 ? su : sd) + (size_t)e * MAT_ELEMS;
#pragma unroll
  for (int i = ty; i < 32; i += 8) t[i][tx] = s[(size_t)(y0 + i) * 2048 + x0 + tx];
  __syncthreads();
  if (which < 2) {
    short* d = dgu + (size_t)e * (2 * MAT_ELEMS);
#pragma unroll
    for (int i = ty; i < 32; i += 8) {
      const int col = x0 + i;
      const int np = ((col >> 5) * 64) + which * 32 + (col & 31);
      d[(size_t)np * 2048 + y0 + tx] = f2bf(t[tx][i]);
    }
  } else {
#pragma unroll
    for (int i = ty; i < 32; i += 8)
      dd[(size_t)(x0 + i) * ((size_t)nexp * 2048) + (size_t)e * 2048 + y0 + tx] = f2bf(t[tx][i]);
  }
}

// ================= 256x256 GEMM core, BK=64, 8 waves (2M x 4N), 8-phase =================
// LDS: As/Bs each [2 buf][2 half][128 rows][64 shorts] = 64KB each.
// Swizzle: physical 16B-chunk = logical ^ (row&7); inverse applied on global src.
// Per iter = 2 K-tiles (K=128). vmcnt(4) + barrier only at phases 4 and 8.
__device__ __forceinline__ void gemm_core8(
    const short* __restrict__ Ab, const short* __restrict__ Bb,
    const int ld, const int T,   // T = K/64 tiles, even
    short* As, short* Bs, f32x4 (&acc)[8][4])
{
  const int tid = threadIdx.x;
  const int w = tid >> 6, lane = tid & 63;
  const int wm = w >> 2, wn = w & 3;
  const int r = lane & 15, g4 = lane >> 4;
  const int l3 = lane >> 3, l7 = lane & 7;

  // staging: per-thread global src offset (shot0 of a half-tile); shot1 += 8*ld
  const size_t sSrc = (size_t)(w * 16 + l3) * ld + (size_t)((l7 ^ l3) * 8);
  const int wdst = w * 1024;   // shorts, wave-uniform; shot1 += 512

  // fragment read addresses (bytes)
  const unsigned aB = LDS_OFF(As), bB = LDS_OFF(Bs);
  unsigned aro[2][4], bro[2][2], csb[2];
#pragma unroll
  for (int mh = 0; mh < 2; mh++)
#pragma unroll
    for (int mq = 0; mq < 4; mq++)
      aro[mh][mq] = aB + (unsigned)(wm * 16384 + (mh * 64 + mq * 16 + r) * 128);
#pragma unroll
  for (int nh = 0; nh < 2; nh++)
#pragma unroll
    for (int nq = 0; nq < 2; nq++) {
      const int row = wn * 64 + nh * 32 + nq * 16 + r;
      bro[nh][nq] = bB + (unsigned)((row >> 7) * 16384 + (row & 127) * 128);
    }
#pragma unroll
  for (int kk = 0; kk < 2; kk++)
    csb[kk] = (unsigned)((((kk * 4 + g4) ^ (r & 7)) * 16));

#pragma unroll
  for (int i = 0; i < 8; i++)
#pragma unroll
    for (int jn = 0; jn < 4; jn++) acc[i][jn] = (f32x4){0.f, 0.f, 0.f, 0.f};

#define STG(MAT_LDS, MAT_G, tt, hh) do { \
  const short* gsrc_ = (MAT_G) + (size_t)(hh) * 128 * ld + (size_t)(tt) * 64 + sSrc; \
  short* ldst_ = (MAT_LDS) + ((tt) & 1) * 16384 + (hh) * 8192 + wdst; \
  GLOAD_LDS(gsrc_, ldst_); \
  GLOAD_LDS(gsrc_ + (size_t)8 * ld, ldst_ + 512); \
} while (0)

#define RD_A(mh, b32) do { \
  _Pragma("unroll") \
  for (int mq = 0; mq < 4; mq++) \
    _Pragma("unroll") \
    for (int kk = 0; kk < 2; kk++) \
      DS_READ_B128(Ar[mq * 2 + kk], aro[mh][mq] + (b32) + csb[kk]); \
} while (0)

#define RD_B(nh, DST, b32) do { \
  _Pragma("unroll") \
  for (int nq = 0; nq < 2; nq++) \
    _Pragma("unroll") \
    for (int kk = 0; kk < 2; kk++) \
      DS_READ_B128(DST[nq * 2 + kk], bro[nh][nq] + (b32) + csb[kk]); \
} while (0)

#define MM(BV, mh, nh) do { \
  __builtin_amdgcn_s_setprio(1); \
  _Pragma("unroll") \
  for (int mq = 0; mq < 4; mq++) \
    _Pragma("unroll") \
    for (int nq = 0; nq < 2; nq++) \
      _Pragma("unroll") \
      for (int kk = 0; kk < 2; kk++) \
        asm volatile("v_mfma_f32_16x16x32_bf16 %0, %1, %2, %0" \
                     : "+v"(acc[(mh) * 4 + mq][(nh) * 2 + nq]) \
                     : "v"(Ar[mq * 2 + kk]), "v"(BV[nq * 2 + kk])); \
  __builtin_amdgcn_s_setprio(0); \
} while (0)

  // prologue: stage 0·Bh0, 0·Bh1, 0·Ah0, 0·Ah1, 1·Bh0, 1·Bh1 (12 loads)
  STG(Bs, Bb, 0, 0); STG(Bs, Bb, 0, 1);
  STG(As, Ab, 0, 0); STG(As, Ab, 0, 1);
  STG(Bs, Bb, 1, 0); STG(Bs, Bb, 1, 1);
  VMC(4);            // tile 0 fully resident
  BAR();

  short8 Ar[8], B0[4], B1[4];

  for (int t = 0; t < T; t += 2) {
    const int t1 = t + 1;
    const int t2 = (t + 2 < T) ? t + 2 : 0;   // wrap: harmless re-stage
    const int t3 = (t + 3 < T) ? t + 3 : 1;
    // ---- P1: A(mh0)+B(nh0) of tile t (buf0) ; stage (t1)Ah0 ----
    RD_A(0, 0u); RD_B(0, B0, 0u);
    STG(As, Ab, t1, 0);
    BAR(); LGKM0(); MM(B0, 0, 0); BAR();
    // ---- P2: B(nh1) ; stage (t1)Ah1 ----
    RD_B(1, B1, 0u);
    STG(As, Ab, t1, 1);
    BAR(); LGKM0(); MM(B1, 0, 1); BAR();
    // ---- P3: A(mh1) ; stage (t2)Bh0 ----
    RD_A(1, 0u);
    STG(Bs, Bb, t2, 0);
    BAR(); LGKM0(); MM(B0, 1, 0); BAR();
    // ---- P4: stage (t2)Bh1 ; MFMA ; vmcnt(4) gate for tile t+1 ----
    STG(Bs, Bb, t2, 1);
    BAR(); MM(B1, 1, 1);
    VMC(4);
    BAR();
    // ---- P5: A(mh0)+B(nh0) of tile t+1 (buf1) ; stage (t2)Ah0 ----
    RD_A(0, 32768u); RD_B(0, B0, 32768u);
    STG(As, Ab, t2, 0);
    BAR(); LGKM0(); MM(B0, 0, 0); BAR();
    // ---- P6: B(nh1) ; stage (t2)Ah1 ----
    RD_B(1, B1, 32768u);
    STG(As, Ab, t2, 1);
    BAR(); LGKM0(); MM(B1, 0, 1); BAR();
    // ---- P7: A(mh1) ; stage (t3)Bh0 ----
    RD_A(1, 32768u);
    STG(Bs, Bb, t3, 0);
    BAR(); LGKM0(); MM(B0, 1, 0); BAR();
    // ---- P8: stage (t3)Bh1 ; MFMA ; vmcnt(4) gate for tile t+2 ----
    STG(Bs, Bb, t3, 1);
    BAR(); MM(B1, 1, 1);
    VMC(4);
    BAR();
  }
  VMC(0);
#undef STG
#undef RD_A
#undef RD_B
#undef MM
  __builtin_amdgcn_sched_barrier(0);
  asm volatile("s_nop 7\n\ts_nop 7" ::: "memory");
}

// ---------------- fused gate+up kernel ----------------
// B' per expert: 4096 rows (32-col interleave). Wave (wn,nh): nh=0 gate, nh=1 up.
template<int BATCHED>
__global__ __launch_bounds__(512, 1) void fused_gu_kernel(
    const short* __restrict__ xb, const short* __restrict__ Bgu,
    short* __restrict__ h, const float* __restrict__ rw, int e_param)
{
  __shared__ short As_[32768];
  __shared__ short Bs_[32768];
  int bx, by, e;
  const short* Bp;
  long hstride, hcol0;
  if (BATCHED) {
    const int swz = (blockIdx.x & 7) * 256 + (blockIdx.x >> 3);
    e = swz >> 8;
    const int rem = swz & 255;
    by = rem >> 4; bx = rem & 15;
    Bp = Bgu + (size_t)e * (2 * MAT_ELEMS);
    hstride = 16384; hcol0 = (long)e * 2048;
  } else {
    const int swz = (blockIdx.x & 7) * 32 + (blockIdx.x >> 3);
    e = e_param;
    by = swz >> 4; bx = swz & 15;
    Bp = Bgu;
    hstride = 2048; hcol0 = 0;
  }
  const int m0 = by * 256, n0 = bx * 256;

  f32x4 acc[8][4];
  gemm_core8(xb + (size_t)m0 * 2048, Bp + (size_t)n0 * 2048, 2048, 32, As_, Bs_, acc);

  const int tid = threadIdx.x;
  const int w = tid >> 6, lane = tid & 63;
  const int wm = w >> 2, wn = w & 3;
  const int r = lane & 15, g4 = lane >> 4;
#pragma unroll
  for (int mi = 0; mi < 8; mi++) {
#pragma unroll
    for (int j = 0; j < 4; j++) {
      const int row = m0 + wm * 128 + (mi >> 2) * 64 + (mi & 3) * 16 + g4 * 4 + j;
      const float wt = rw[(size_t)row * 8 + e];
#pragma unroll
      for (int nq = 0; nq < 2; nq++) {
        const float g = acc[mi][nq][j];        // nh=0 (gate)
        const float u = acc[mi][2 + nq][j];    // nh=1 (up)
        const float hv = (g / (1.f + __expf(-g))) * u * wt;
        const long c = (long)(bx * 4 + wn) * 32 + nq * 16 + r;
        h[(size_t)row * hstride + hcol0 + c] = f2bf(hv);
      }
    }
  }
}

// ---------------- down kernel (split-K=2, f32 partials) ----------------
template<int BATCHED>
__global__ __launch_bounds__(512, 1) void down_kernel(
    const short* __restrict__ h, const short* __restrict__ WdT,
    float* __restrict__ part)
{
  __shared__ short As_[32768];
  __shared__ short Bs_[32768];
  const int swz = (blockIdx.x & 7) * 32 + (blockIdx.x >> 3);
  const int z = swz >> 7;
  const int rem = swz & 127;
  const int by = rem >> 3, bx = rem & 7;
  const int m0 = by * 256, n0 = bx * 256;
  const int ld = BATCHED ? 16384 : 2048;
  const int kz = BATCHED ? 8192 : 1024;
  const int T = kz / 64;

  f32x4 acc[8][4];
  gemm_core8(h + (size_t)m0 * ld + (size_t)z * kz,
             WdT + (size_t)n0 * ld + (size_t)z * kz, ld, T, As_, Bs_, acc);

  float* pz = part + (size_t)z * BT_NUM * 2048;
  const int tid = threadIdx.x;
  const int w = tid >> 6, lane = tid & 63;
  const int wm = w >> 2, wn = w & 3;
  const int r = lane & 15, g4 = lane >> 4;
#pragma unroll
  for (int mi = 0; mi < 8; mi++) {
#pragma unroll
    for (int ni = 0; ni < 4; ni++) {
      const int col = n0 + wn * 64 + (ni >> 1) * 32 + (ni & 1) * 16 + r;
#pragma unroll
      for (int j = 0; j < 4; j++) {
        const int row = m0 + wm * 128 + (mi >> 2) * 64 + (mi & 3) * 16 + g4 * 4 + j;
        pz[(size_t)row * 2048 + col] = acc[mi][ni][j];
      }
    }
  }
}

// ---------------- add partials ----------------
__global__ __launch_bounds__(256) void add2_kernel(
    const float* __restrict__ p0, const float* __restrict__ p1,
    float* __restrict__ out, int accum)
{
  const size_t i = ((size_t)blockIdx.x * 256 + threadIdx.x) * 4;
  f32x4 v = *(const f32x4*)(p0 + i) + *(const f32x4*)(p1 + i);
  if (accum) v += *(const f32x4*)(out + i);
  *(f32x4*)(out + i) = v;
}

extern "C" void kernel_launch(void* const* d_in, const int* in_sizes, int n_in,
                              void* d_out, int out_size, void* d_ws, size_t ws_size,
                              hipStream_t stream)
{
  const float* x  = (const float*)d_in[0];
  const float* Wg = (const float*)d_in[1];
  const float* Wu = (const float*)d_in[2];
  const float* Wd = (const float*)d_in[3];
  const float* Wr = (const float*)d_in[4];
  const float* tp = (const float*)d_in[5];
  float* out = (float*)d_out;

  char* ws = (char*)d_ws;
  const size_t SZ_RW = (size_t)BT_NUM * 8 * 4;
  const size_t SZ_XB = (size_t)BT_NUM * 2048 * 2;
  const size_t SZ_BGU_E = 2 * MAT_ELEMS * 2;

  const size_t FULL = SZ_RW + SZ_XB + 8 * SZ_BGU_E
                    + (size_t)2048 * 16384 * 2
                    + (size_t)BT_NUM * 16384 * 2;

  float* rw = (float*)ws;
  router_kernel<<<BT_NUM, 256, 0, stream>>>(x, Wr, tp, rw);

  if (ws_size >= FULL) {
    size_t off = SZ_RW;
    short* xb  = (short*)(ws + off); off += SZ_XB;
    short* Bgu = (short*)(ws + off); off += 8 * SZ_BGU_E;
    short* WdT = (short*)(ws + off); off += (size_t)2048 * 16384 * 2;
    short* h   = (short*)(ws + off);
    float* part = (float*)Bgu;   // reuse B' region after fused_gu

    cvt_x_kernel<<<4096, 256, 0, stream>>>(x, xb);
    transpose_cvt_kernel<<<dim3(64, 64, 24), dim3(32, 8), 0, stream>>>(
        Wg, Wu, Wd, Bgu, WdT, 8);
    fused_gu_kernel<1><<<2048, 512, 0, stream>>>(xb, Bgu, h, rw, 0);
    down_kernel<1><<<256, 512, 0, stream>>>(h, WdT, part);
    add2_kernel<<<8192, 256, 0, stream>>>(part, part + (size_t)BT_NUM * 2048, out, 0);
  } else {
    size_t off = SZ_RW;
    short* xb  = (short*)(ws + off); off += SZ_XB;
    short* Bgu = (short*)(ws + off); off += SZ_BGU_E;
    short* WdT = (short*)(ws + off); off += MAT_ELEMS * 2;
    short* h   = (short*)(ws + off); off += (size_t)BT_NUM * 2048 * 2;
    float* part = (float*)(ws + off);

    cvt_x_kernel<<<4096, 256, 0, stream>>>(x, xb);
    for (int e = 0; e < 8; e++) {
      transpose_cvt_kernel<<<dim3(64, 64, 3), dim3(32, 8), 0, stream>>>(
          Wg + (size_t)e * MAT_ELEMS, Wu + (size_t)e * MAT_ELEMS,
          Wd + (size_t)e * MAT_ELEMS, Bgu, WdT, 1);
      fused_gu_kernel<0><<<256, 512, 0, stream>>>(xb, Bgu, h, rw, e);
      down_kernel<0><<<256, 512, 0, stream>>>(h, WdT, part);
      add2_kernel<<<8192, 256, 0, stream>>>(part, part + (size_t)BT_NUM * 2048, out, e > 0);
    }
  }
}